// Round 2
// baseline (1299.750 us; speedup 1.0000x reference)
//
#include <hip/hip_runtime.h>

typedef unsigned short u16;
typedef unsigned int u32;
typedef float f32x4 __attribute__((ext_vector_type(4)));
typedef short bf16x8 __attribute__((ext_vector_type(8)));

// ---- geometry ----
// B=512, DIM=384, RES=7, N=49, NH=8, KD=32, D=128, DH=1024, NHKD=256, HID=1536
// M = B*49 = 25088
// max-scalar table (ws offset 0):
// 0 Mq 1 Mk 2 Mv 3 Mvl 4 Mpre_th1 5 Mattn 6 Mpostsm 7 Mres_abs 8 Mres_pos
// 9 Mproj 10 Mx1 11 Mh1(relu) 12 Mmid(relu) 13 Mfc2 14 Mfinal

__device__ __forceinline__ u16 f2bf(float f){
  u32 x = __float_as_uint(f);
  x += 0x7fffu + ((x >> 16) & 1u);
  return (u16)(x >> 16);
}
__device__ __forceinline__ float bf2f(u16 u){ return __uint_as_float(((u32)u) << 16); }
__device__ __forceinline__ float qsc(float m, float qmax){ return fmaxf(m / qmax, 1e-8f); }
__device__ __forceinline__ float fq(float x, float s){
  return fminf(fmaxf(rintf(x / s), -127.f), 127.f) * s;
}
__device__ __forceinline__ void blockMaxTo(float* target, float v){
  __shared__ float red[256];
  __syncthreads();
  red[threadIdx.x] = v;
  __syncthreads();
  for (int s = blockDim.x >> 1; s > 0; s >>= 1){
    if ((int)threadIdx.x < s) red[threadIdx.x] = fmaxf(red[threadIdx.x], red[threadIdx.x + s]);
    __syncthreads();
  }
  if (threadIdx.x == 0) atomicMax((int*)target, __float_as_int(red[0]));
}

__global__ void zeromx(float* mx){
  if (threadIdx.x < 64) mx[threadIdx.x] = 0.f;
}

// ---------------- weight quantization (per-output-channel) ----------------
__global__ __launch_bounds__(128) void wquant(
    const float* wq, const float* wk, const float* wv, const float* wproj,
    const float* wfc1, const float* wfc2, const float* wvl, const float* wmid,
    const float* wth1, const float* wth2,
    const float* bq, const float* bk, const float* bv,
    u16* wqkv_b, u16* wproj_b, u16* wfc1_b, u16* wfc2_b,
    float* wvl_q, float* wmid_q, float* wth1_q, float* wth2_q, float* biasqkv)
{
  const int tid = threadIdx.x;
  const int bid = blockIdx.x;
  if (bid == 6416){
    for (int j = tid; j < 1536; j += 128){
      float v = (j < 256) ? bq[j] : ((j < 512) ? bk[j - 256] : bv[j - 512]);
      biasqkv[j] = v;
    }
    return;
  }
  const int rows[10] = {256,256,1024,384,1536,384,1024,1536,8,8};
  int seg = 0, r = bid;
  while (r >= rows[seg]) { r -= rows[seg]; ++seg; }
  int len = 0;
  const float* src = nullptr; u16* db = nullptr; float* df = nullptr;
  switch (seg){
    case 0: len = 384;  src = wq    + r*384;  db = wqkv_b + r*384;        break;
    case 1: len = 384;  src = wk    + r*384;  db = wqkv_b + (256+r)*384;  break;
    case 2: len = 384;  src = wv    + r*384;  db = wqkv_b + (512+r)*384;  break;
    case 3: len = 1024; src = wproj + r*1024; db = wproj_b + r*1024;      break;
    case 4: len = 384;  src = wfc1  + r*384;  db = wfc1_b + r*384;        break;
    case 5: len = 1536; src = wfc2  + r*1536; db = wfc2_b + r*1536;       break;
    case 6: len = 9;    src = wvl   + r*9;    df = wvl_q + r*9;           break;
    case 7: len = 9;    src = wmid  + r*9;    df = wmid_q + r*9;          break;
    case 8: len = 8;    src = wth1  + r*8;    df = wth1_q + r*8;          break;
    default: len = 8;   src = wth2  + r*8;    df = wth2_q + r*8;          break;
  }
  float lm = 0.f;
  for (int j = tid; j < len; j += 128) lm = fmaxf(lm, fabsf(src[j]));
  __shared__ float red[128];
  red[tid] = lm; __syncthreads();
  for (int s = 64; s > 0; s >>= 1){
    if (tid < s) red[tid] = fmaxf(red[tid], red[tid + s]);
    __syncthreads();
  }
  float s = fmaxf(red[0] / 127.f, 1e-8f);
  for (int j = tid; j < len; j += 128){
    float v = fminf(fmaxf(rintf(src[j] / s), -127.f), 127.f) * s;
    if (db) db[j] = f2bf(v); else df[j] = v;
  }
}

// ---------------- x (NCHW) -> xT [m=b*49+p][c] bf16 ----------------
__global__ __launch_bounds__(256) void xpose(const float* __restrict__ x, u16* __restrict__ xT){
  const int b = blockIdx.x;
  __shared__ u16 xb[18816];
  const int tid = threadIdx.x;
  for (int j = tid; j < 18816; j += 256) xb[j] = f2bf(x[(size_t)b*18816 + j]);
  __syncthreads();
  for (int j = tid; j < 18816; j += 256){
    int p = j / 384, c = j - p*384;
    xT[(size_t)b*18816 + j] = xb[c*49 + p];
  }
}

// ---------------- bf16 MFMA GEMM: C[M][N] = A[M][K] * Bt[N][K]^T + bias ----------------
// epi: 0 = absmax, 1 = qkv (3 regions by n0), 2 = relu then posmax. C written as bf16.
__global__ __launch_bounds__(256) void gemm_bt(
    const u16* __restrict__ A, const u16* __restrict__ Bt,
    const float* __restrict__ bias, u16* __restrict__ C,
    float* __restrict__ mx, int N, int K, int epi, int region)
{
  __shared__ __align__(16) u16 As[128*64];
  __shared__ __align__(16) u16 Bs[128*64];
  const int tid = threadIdx.x;
  const int lane = tid & 63, wid = tid >> 6;
  const int n0 = blockIdx.x * 128;
  const int m0 = blockIdx.y * 128;
  const int wr = wid >> 1, wc = wid & 1;
  f32x4 acc[4][4] = {};
  const int nsteps = K >> 6;
  for (int s = 0; s < nsteps; ++s){
    const int k0 = s << 6;
    #pragma unroll
    for (int j = 0; j < 4; ++j){
      int boff = j*4096 + tid*16;
      int row = boff >> 7;
      int ce  = (boff & 127) >> 1;
      uint4 va = *(const uint4*)(A  + (size_t)(m0 + row)*K + k0 + ce);
      uint4 vb = *(const uint4*)(Bt + (size_t)(n0 + row)*K + k0 + ce);
      *(uint4*)&As[boff >> 1] = va;
      *(uint4*)&Bs[boff >> 1] = vb;
    }
    __syncthreads();
    #pragma unroll
    for (int kk = 0; kk < 2; ++kk){
      bf16x8 af[4], bfr[4];
      #pragma unroll
      for (int i = 0; i < 4; ++i){
        int ar = wr*64 + i*16 + (lane & 15);
        af[i]  = *(const bf16x8*)&As[ar*64 + kk*32 + (lane >> 4)*8];
        int br = wc*64 + i*16 + (lane & 15);
        bfr[i] = *(const bf16x8*)&Bs[br*64 + kk*32 + (lane >> 4)*8];
      }
      #pragma unroll
      for (int i = 0; i < 4; ++i){
        #pragma unroll
        for (int j = 0; j < 4; ++j){
          acc[i][j] = __builtin_amdgcn_mfma_f32_16x16x32_bf16(af[i], bfr[j], acc[i][j], 0, 0, 0);
        }
      }
    }
    __syncthreads();
  }
  float lm = 0.f;
  #pragma unroll
  for (int i = 0; i < 4; ++i){
    int rbase = m0 + wr*64 + i*16 + ((lane >> 4) << 2);
    #pragma unroll
    for (int j = 0; j < 4; ++j){
      int col = n0 + wc*64 + j*16 + (lane & 15);
      float bv = bias[col];
      #pragma unroll
      for (int q = 0; q < 4; ++q){
        float v = acc[i][j][q] + bv;
        if (epi == 2) v = fmaxf(v, 0.f);
        C[(size_t)(rbase + q)*N + col] = f2bf(v);
        lm = fmaxf(lm, (epi == 2) ? v : fabsf(v));
      }
    }
  }
  int reg = region;
  if (epi == 1) reg = (n0 < 256) ? 0 : ((n0 < 512) ? 1 : 2);
  blockMaxTo(&mx[reg], lm);
}

// ---------------- depthwise 3x3 local-V absmax only (no output) ----------------
__global__ __launch_bounds__(128) void vlmax(
    const u16* __restrict__ qkv, const float* __restrict__ wv9,
    const float* __restrict__ bvl, float* __restrict__ mx)
{
  const int cc = blockIdx.x, b = blockIdx.y;   // cc = head (128-ch group)
  __shared__ float xin[49*132];
  const float sv = qsc(mx[2], 127.f);
  const int tid = threadIdx.x;
  for (int j = tid; j < 49*128; j += 128){
    int p = j >> 7, c = j & 127;
    xin[p*132 + c] = fq(bf2f(qkv[(size_t)(b*49 + p)*1536 + 512 + cc*128 + c]), sv);
  }
  __syncthreads();
  const int c = tid;
  float w9[9];
  #pragma unroll
  for (int i = 0; i < 9; ++i) w9[i] = wv9[(cc*128 + c)*9 + i];
  const float bb = bvl[cc*128 + c];
  float col[49];
  #pragma unroll
  for (int p = 0; p < 49; ++p) col[p] = xin[p*132 + c];
  float lm = 0.f;
  #pragma unroll
  for (int p = 0; p < 49; ++p){
    const int py = p / 7, px = p % 7;
    float acc = bb;
    #pragma unroll
    for (int dy = 0; dy < 3; ++dy){
      const int yy = py + dy - 1;
      if (yy < 0 || yy > 6) continue;
      #pragma unroll
      for (int dx = 0; dx < 3; ++dx){
        const int xx = px + dx - 1;
        if (xx < 0 || xx > 6) continue;
        acc += col[yy*7 + xx] * w9[dy*3 + dx];
      }
    }
    lm = fmaxf(lm, fabsf(acc));
  }
  blockMaxTo(&mx[3], lm);
}

// ---------------- S = q*k^T*scale + bias ----------------
__global__ __launch_bounds__(256) void attn_qk(
    const u16* __restrict__ qkv, const float* __restrict__ biases,
    const int* __restrict__ idxs, float* __restrict__ S, float* __restrict__ mx)
{
  const int h = blockIdx.x, b = blockIdx.y;
  __shared__ float qs[49*32];
  __shared__ float ks[49*33];
  __shared__ float brow[49];
  const float sq = qsc(mx[0], 127.f), sk = qsc(mx[1], 127.f);
  const int tid = threadIdx.x;
  for (int j = tid; j < 49*32; j += 256){
    int n = j >> 5, kd = j & 31;
    size_t base = (size_t)(b*49 + n)*1536;
    qs[j] = fq(bf2f(qkv[base + h*32 + kd]), sq);
    ks[n*33 + kd] = fq(bf2f(qkv[base + 256 + h*32 + kd]), sk);
  }
  if (tid < 49) brow[tid] = biases[h*49 + tid];
  __syncthreads();
  float lm = 0.f;
  const float scale = 0.17677669529663687f;
  for (int t = tid; t < 2401; t += 256){
    int n = t / 49, m = t - n*49;
    float acc = 0.f;
    #pragma unroll
    for (int kd = 0; kd < 32; ++kd) acc += qs[n*32 + kd] * ks[m*33 + kd];
    float v = acc * scale + brow[idxs[t]];
    S[((size_t)b*8 + h)*2401 + t] = v;
    lm = fmaxf(lm, fabsf(v));
  }
  blockMaxTo(&mx[4], lm);
}

// ---------------- talking head 1 (IN-PLACE on S; no restrict!) ----------------
__global__ __launch_bounds__(256) void th1k(
    const float* S, const float* w1, const float* b1, float* T, float* mx)
{
  const int b = blockIdx.y;
  const int j = blockIdx.x*256 + threadIdx.x;
  __shared__ float wsh[64];
  __shared__ float bsh[8];
  if (threadIdx.x < 64) wsh[threadIdx.x] = w1[threadIdx.x];
  if (threadIdx.x < 8)  bsh[threadIdx.x] = b1[threadIdx.x];
  __syncthreads();
  float lm = 0.f;
  if (j < 2401){
    const float s1 = qsc(mx[4], 127.f);
    float a[8];
    #pragma unroll
    for (int h = 0; h < 8; ++h) a[h] = fq(S[((size_t)b*8 + h)*2401 + j], s1);
    float o8[8];
    #pragma unroll
    for (int o = 0; o < 8; ++o){
      float t = bsh[o];
      #pragma unroll
      for (int h = 0; h < 8; ++h) t += wsh[o*8 + h] * a[h];
      o8[o] = t;
      lm = fmaxf(lm, fabsf(t));
    }
    #pragma unroll
    for (int o = 0; o < 8; ++o) T[((size_t)b*8 + o)*2401 + j] = o8[o];
  }
  blockMaxTo(&mx[5], lm);
}

// ---------------- int softmax (I-BERT) + talking head 2 (IN-PLACE) ----------------
__global__ __launch_bounds__(256) void smth2(
    const float* T, const float* w2, const float* b2, float* U, float* mx)
{
  const int b = blockIdx.x;
  __shared__ float P[19208];
  __shared__ float wsh[64];
  __shared__ float bsh[8];
  const float sa = qsc(mx[5], 127.f);
  const int tid = threadIdx.x;
  if (tid < 64) wsh[tid] = w2[tid];
  if (tid < 8)  bsh[tid] = b2[tid];
  for (int j = tid; j < 19208; j += 256){
    float v = T[(size_t)b*19208 + j];
    P[j] = fminf(fmaxf(rintf(v / sa), -127.f), 127.f);   // integer-valued
  }
  __syncthreads();
  const float x0 = floorf(-0.6931f / sa);
  const float bi = floorf((0.96963238f / 0.35815147f) / sa);
  const float ci = floorf((1.0f / 0.35815147f) / (sa * sa));
  const float Kc = ((0.35815147f * sa) * sa) * (1.f/1073741824.f);
  const float maxv = (ci * 1073741824.f) * Kc;     // analytic global max of exp tensor
  const float se = fmaxf(maxv / 32767.f, 1e-8f);
  const float clampLo = 30.f * x0;
  for (int row = tid; row < 392; row += 256){
    float* pr = &P[row*49];
    float rmax = pr[0];
    for (int m = 1; m < 49; ++m) rmax = fmaxf(rmax, pr[m]);
    float rsum = 0.f;
    for (int m = 0; m < 49; ++m){
      float xi = pr[m] - rmax;
      xi = fmaxf(xi, clampLo);
      float qd = floorf(xi / x0);
      float r = xi - x0*qd;
      float z = (r + bi)*r + ci;
      float ei = floorf(z * exp2f(30.f - qd));
      ei = fmaxf(ei, 0.f);
      float t = ei * Kc;
      float e2 = fminf(fmaxf(rintf(t / se), -32767.f), 32767.f);
      float eint = (e2 * se) / se;
      pr[m] = eint;
      rsum += eint;
    }
    const float factor = floorf(4294967296.f / rsum);
    for (int m = 0; m < 49; ++m){
      pr[m] = floorf((pr[m] * factor) * (1.f/65536.f)) * (1.f/65536.f);
    }
  }
  __syncthreads();
  float lm = 0.f;
  for (int j = tid; j < 19208; j += 256){
    int o = j / 2401, rem = j - o*2401;
    float t = bsh[o];
    #pragma unroll
    for (int h = 0; h < 8; ++h) t += wsh[o*8 + h] * P[h*2401 + rem];
    U[(size_t)b*19208 + j] = t;
    lm = fmaxf(lm, fabsf(t));
  }
  blockMaxTo(&mx[6], lm);
}

// ---------------- out = attn_q @ v_q + fq(dwconv(v_q)), abs/pos max ----------------
__global__ __launch_bounds__(256) void attn_v(
    const u16* __restrict__ qkv, const float* __restrict__ U,
    const float* __restrict__ wv9, const float* __restrict__ bvl,
    u16* __restrict__ av, float* __restrict__ mx)
{
  const int h = blockIdx.x, b = blockIdx.y;
  __shared__ float As2[2401];
  __shared__ float Vq[49*132];
  __shared__ float w9s[128*9];
  __shared__ float bvs[128];
  const float s3 = qsc(mx[6], 127.f), sv = qsc(mx[2], 127.f), svl = qsc(mx[3], 127.f);
  const int tid = threadIdx.x;
  for (int j = tid; j < 2401; j += 256) As2[j] = fq(U[((size_t)b*8 + h)*2401 + j], s3);
  for (int j = tid; j < 6272; j += 256){
    int m = j >> 7, d = j & 127;
    Vq[m*132 + d] = fq(bf2f(qkv[(size_t)(b*49 + m)*1536 + 512 + h*128 + d]), sv);
  }
  for (int j = tid; j < 1152; j += 256) w9s[j] = wv9[h*1152 + j];
  if (tid < 128) bvs[tid] = bvl[h*128 + tid];
  __syncthreads();
  float lm = 0.f, lmp = 0.f;
  for (int t = tid; t < 784; t += 256){
    int n = t >> 4, dg = t & 15;
    int d0 = dg * 8;
    f32x4 a0 = {}, a1 = {};
    for (int m = 0; m < 49; ++m){
      float a = As2[n*49 + m];
      const f32x4* vp = (const f32x4*)&Vq[m*132 + d0];
      a0 += a * vp[0];
      a1 += a * vp[1];
    }
    // local depthwise 3x3 branch, recomputed + quantized with svl
    const int py = n / 7, px = n % 7;
    float r8[8];
    #pragma unroll
    for (int u = 0; u < 8; ++u){
      int c = d0 + u;
      float acc = bvs[c];
      #pragma unroll
      for (int dy = 0; dy < 3; ++dy){
        const int yy = py + dy - 1;
        if (yy < 0 || yy > 6) continue;
        #pragma unroll
        for (int dx = 0; dx < 3; ++dx){
          const int xx = px + dx - 1;
          if (xx < 0 || xx > 6) continue;
          acc += Vq[(yy*7 + xx)*132 + c] * w9s[c*9 + dy*3 + dx];
        }
      }
      r8[u] = fq(acc, svl);
    }
    #pragma unroll
    for (int u = 0; u < 4; ++u){
      float v0 = a0[u] + r8[u];
      float v1 = a1[u] + r8[4 + u];
      av[(size_t)(b*49 + n)*1024 + h*128 + d0 + u] = f2bf(v0);
      av[(size_t)(b*49 + n)*1024 + h*128 + d0 + 4 + u] = f2bf(v1);
      lm = fmaxf(lm, fmaxf(fabsf(v0), fabsf(v1)));
      lmp = fmaxf(lmp, fmaxf(v0, v1));
    }
  }
  blockMaxTo(&mx[7], lm);
  blockMaxTo(&mx[8], lmp);
}

// ---------------- av -> quant(av_res) -> relu -> quant(proj_in) (IN-PLACE) ----------------
__global__ void av2bf(const u16* av, u16* ap, const float* mx){
  const float sres = qsc(mx[7], 127.f);
  const float posq = fq(mx[8], sres);
  const float spi = fmaxf(posq / 127.f, 1e-8f);
  const size_t n = (size_t)25088*1024;
  for (size_t i = (size_t)blockIdx.x*blockDim.x + threadIdx.x; i < n; i += (size_t)gridDim.x*blockDim.x){
    float r1 = fq(bf2f(av[i]), sres);
    float r2 = fmaxf(r1, 0.f);
    ap[i] = f2bf(fq(r2, spi));
  }
}

// ---------------- y1 = x + ls1*quant(proj), absmax ----------------
__global__ __launch_bounds__(256) void res1max(
    const float* __restrict__ x, const u16* __restrict__ praw,
    const float* __restrict__ ls1, float* __restrict__ y1, float* __restrict__ mx)
{
  const int b = blockIdx.x;
  __shared__ float xs[18816];
  __shared__ float lss[384];
  const float sp = qsc(mx[9], 127.f);
  const int tid = threadIdx.x;
  for (int j = tid; j < 18816; j += 256) xs[j] = x[(size_t)b*18816 + j];
  for (int j = tid; j < 384; j += 256) lss[j] = ls1[j];
  __syncthreads();
  float lm = 0.f;
  for (int j = tid; j < 18816; j += 256){
    int p = j / 384, c = j - p*384;
    float y = xs[c*49 + p] + lss[c] * fq(bf2f(praw[(size_t)b*18816 + j]), sp);
    y1[(size_t)b*18816 + j] = y;
    lm = fmaxf(lm, fabsf(y));
  }
  blockMaxTo(&mx[10], lm);
}

// ---------------- x1 = quant(y1): fp32 (in d_out) + bf16 copies ----------------
__global__ void qx1(const float* __restrict__ y1, float* __restrict__ x1f, u16* __restrict__ x1b,
                    const float* __restrict__ mx){
  const float s = qsc(mx[10], 127.f);
  const size_t n = (size_t)9633792;
  for (size_t i = (size_t)blockIdx.x*blockDim.x + threadIdx.x; i < n; i += (size_t)gridDim.x*blockDim.x){
    float v = fq(y1[i], s);
    x1f[i] = v;
    x1b[i] = f2bf(v);
  }
}

// ---------------- depthwise 3x3 (mid conv) + relu (IN-PLACE on h1) ----------------
__global__ __launch_bounds__(128) void dw_mid(
    const u16* h1, const float* wm9, const float* bmid, u16* m1, float* mx)
{
  const int cc = blockIdx.x, b = blockIdx.y;
  __shared__ float xin[49*132];
  const float sh = qsc(mx[11], 127.f);
  const int tid = threadIdx.x;
  for (int j = tid; j < 49*128; j += 128){
    int p = j >> 7, c = j & 127;
    xin[p*132 + c] = fq(bf2f(h1[(size_t)(b*49 + p)*1536 + cc*128 + c]), sh);
  }
  __syncthreads();
  const int c = tid;
  float w9[9];
  #pragma unroll
  for (int i = 0; i < 9; ++i) w9[i] = wm9[(cc*128 + c)*9 + i];
  const float bb = bmid[cc*128 + c];
  float col[49];
  #pragma unroll
  for (int p = 0; p < 49; ++p) col[p] = xin[p*132 + c];
  float lm = 0.f;
  #pragma unroll
  for (int p = 0; p < 49; ++p){
    const int py = p / 7, px = p % 7;
    float acc = bb;
    #pragma unroll
    for (int dy = 0; dy < 3; ++dy){
      const int yy = py + dy - 1;
      if (yy < 0 || yy > 6) continue;
      #pragma unroll
      for (int dx = 0; dx < 3; ++dx){
        const int xx = px + dx - 1;
        if (xx < 0 || xx > 6) continue;
        acc += col[yy*7 + xx] * w9[dy*3 + dx];
      }
    }
    acc = fmaxf(acc, 0.f);
    m1[(size_t)(b*49 + p)*1536 + cc*128 + c] = f2bf(acc);
    lm = fmaxf(lm, acc);
  }
  blockMaxTo(&mx[12], lm);
}

// ---------------- mid -> quant -> bf16 (IN-PLACE) ----------------
__global__ void mid2bf(const u16* m1, u16* mb, const float* mx){
  const float s = qsc(mx[12], 127.f);
  const size_t n = (size_t)25088*1536;
  for (size_t i = (size_t)blockIdx.x*blockDim.x + threadIdx.x; i < n; i += (size_t)gridDim.x*blockDim.x){
    mb[i] = f2bf(fq(bf2f(m1[i]), s));
  }
}

// ---------------- y2 = x1 + ls2*quant(fc2), absmax ----------------
__global__ __launch_bounds__(256) void res2max(
    const float* __restrict__ x1f, const u16* __restrict__ f2,
    const float* __restrict__ ls2, float* __restrict__ y2, float* __restrict__ mx)
{
  const float s = qsc(mx[13], 127.f);
  float lm = 0.f;
  const size_t n = (size_t)9633792;
  for (size_t i = (size_t)blockIdx.x*blockDim.x + threadIdx.x; i < n; i += (size_t)gridDim.x*blockDim.x){
    int c = (int)(i % 384);
    float y = x1f[i] + ls2[c] * fq(bf2f(f2[i]), s);
    y2[i] = y;
    lm = fmaxf(lm, fabsf(y));
  }
  blockMaxTo(&mx[14], lm);
}

// ---------------- out2 = quant(y2), transpose to NCHW, plus out_sf ----------------
__global__ __launch_bounds__(256) void finalout(
    const float* __restrict__ y2, float* __restrict__ out, const float* __restrict__ mx)
{
  const int b = blockIdx.x;
  __shared__ float os[18816];
  const float s = qsc(mx[14], 127.f);
  const int tid = threadIdx.x;
  for (int j = tid; j < 18816; j += 256){
    int p = j / 384, c = j - p*384;
    os[c*49 + p] = fq(y2[(size_t)b*18816 + j], s);
  }
  __syncthreads();
  for (int j = tid; j < 18816; j += 256) out[(size_t)b*18816 + j] = os[j];
  if (b == 0 && tid == 0) out[9633792] = s;
}

extern "C" void kernel_launch(void* const* d_in, const int* in_sizes, int n_in,
                              void* d_out, int out_size, void* d_ws, size_t ws_size,
                              hipStream_t stream)
{
  (void)in_sizes; (void)n_in; (void)out_size; (void)ws_size;
  const float* x    = (const float*)d_in[0];
  const float* wq   = (const float*)d_in[2];
  const float* bq   = (const float*)d_in[3];
  const float* wk   = (const float*)d_in[4];
  const float* bk   = (const float*)d_in[5];
  const float* wv   = (const float*)d_in[6];
  const float* bv   = (const float*)d_in[7];
  const float* wvl  = (const float*)d_in[8];
  const float* bvl  = (const float*)d_in[9];
  const float* ab   = (const float*)d_in[10];
  const float* wth1 = (const float*)d_in[11];
  const float* bth1 = (const float*)d_in[12];
  const float* wth2 = (const float*)d_in[13];
  const float* bth2 = (const float*)d_in[14];
  const float* wproj= (const float*)d_in[15];
  const float* bproj= (const float*)d_in[16];
  const float* wfc1 = (const float*)d_in[17];
  const float* bfc1 = (const float*)d_in[18];
  const float* wmid = (const float*)d_in[19];
  const float* bmid = (const float*)d_in[20];
  const float* wfc2 = (const float*)d_in[21];
  const float* bfc2 = (const float*)d_in[22];
  const float* ls1  = (const float*)d_in[23];
  const float* ls2  = (const float*)d_in[24];
  const int*   idxs = (const int*)d_in[25];
  float* out = (float*)d_out;

  // ---- workspace layout (total 191,480,576 B ~= 183 MiB) ----
  char* w = (char*)d_ws;
  float* mx      = (float*)(w + 0);            // 256 B
  float* biasqkv = (float*)(w + 256);          // 6 KB
  u16* wqkv_b    = (u16*)(w + 6400);           // 1.18 MB
  u16* wproj_b   = (u16*)(w + 1186048);        // 786 KB
  u16* wfc1_b    = (u16*)(w + 1972480);        // 1.18 MB
  u16* wfc2_b    = (u16*)(w + 3152128);        // 1.18 MB
  float* wvl_q   = (float*)(w + 4331776);      // 36.9 KB
  float* wmid_q  = (float*)(w + 4368640);      // 55.3 KB
  float* wth1_q  = (float*)(w + 4423936);      // 256 B
  float* wth2_q  = (float*)(w + 4424192);      // 256 B
  // W1 (19.27 MB): xT -> praw -> x1b -> f2raw  (disjoint lifetimes)
  u16* xT    = (u16*)(w + 4424448);
  u16* praw  = xT;
  u16* x1b   = xT;
  u16* f2raw = xT;
  // W2 (77.07 MB): qkv -> h1 (dw_mid & mid2bf run in place)
  u16* qkv = (u16*)(w + 23692032);
  u16* h1  = qkv;
  // W4 (51.38 MB): avb (av2bf in place; then proj input)
  u16* avb = (u16*)(w + 100762368);
  // W5 (39.34 MB): S (th1k/smth2 in place) -> y1 -> y2
  float* S  = (float*)(w + 152142592);
  float* y1 = S;
  float* y2 = S;
  // x1f (38.54 MB fp32) lives in d_out; overwritten by finalout at the end
  float* x1f = out;

  zeromx<<<1, 64, 0, stream>>>(mx);
  wquant<<<6417, 128, 0, stream>>>(wq, wk, wv, wproj, wfc1, wfc2, wvl, wmid, wth1, wth2,
                                   bq, bk, bv,
                                   wqkv_b, wproj_b, wfc1_b, wfc2_b,
                                   wvl_q, wmid_q, wth1_q, wth2_q, biasqkv);
  xpose<<<512, 256, 0, stream>>>(x, xT);
  gemm_bt<<<dim3(12, 196), 256, 0, stream>>>(xT, wqkv_b, biasqkv, qkv, mx, 1536, 384, 1, 0);
  attn_qk<<<dim3(8, 512), 256, 0, stream>>>(qkv, ab, idxs, S, mx);
  vlmax<<<dim3(8, 512), 128, 0, stream>>>(qkv, wvl_q, bvl, mx);
  th1k<<<dim3(10, 512), 256, 0, stream>>>(S, wth1_q, bth1, S, mx);
  smth2<<<512, 256, 0, stream>>>(S, wth2_q, bth2, S, mx);
  attn_v<<<dim3(8, 512), 256, 0, stream>>>(qkv, S, wvl_q, bvl, avb, mx);
  av2bf<<<2048, 256, 0, stream>>>(avb, avb, mx);
  gemm_bt<<<dim3(3, 196), 256, 0, stream>>>(avb, wproj_b, bproj, praw, mx, 384, 1024, 0, 9);
  res1max<<<512, 256, 0, stream>>>(x, praw, ls1, y1, mx);
  qx1<<<2048, 256, 0, stream>>>(y1, x1f, x1b, mx);
  gemm_bt<<<dim3(12, 196), 256, 0, stream>>>(x1b, wfc1_b, bfc1, h1, mx, 1536, 384, 2, 11);
  dw_mid<<<dim3(12, 512), 128, 0, stream>>>(h1, wmid_q, bmid, h1, mx);
  mid2bf<<<2048, 256, 0, stream>>>(h1, h1, mx);
  gemm_bt<<<dim3(3, 196), 256, 0, stream>>>(h1, wfc2_b, bfc2, f2raw, mx, 384, 1536, 0, 13);
  res2max<<<2048, 256, 0, stream>>>(x1f, f2raw, ls2, y2, mx);
  finalout<<<512, 256, 0, stream>>>(y2, out, mx);
}

// Round 3
// 1021.467 us; speedup vs baseline: 1.2724x; 1.2724x over previous
//
#include <hip/hip_runtime.h>

typedef unsigned short u16;
typedef unsigned int u32;
typedef float f32x4 __attribute__((ext_vector_type(4)));
typedef short bf16x8 __attribute__((ext_vector_type(8)));

// ---- geometry ----
// B=512, DIM=384, RES=7, N=49, NH=8, KD=32, D=128, DH=1024, NHKD=256, HID=1536
// M = B*49 = 25088
// max-scalar table (ws offset 0):
// 0 Mq 1 Mk 2 Mv 3 Mvl 4 Mpre_th1 5 Mattn 6 Mpostsm 7 Mres_abs 8 Mres_pos
// 9 Mproj 10 Mx1 11 Mh1(relu) 12 Mmid(relu) 13 Mfc2 14 Mfinal

__device__ __forceinline__ u16 f2bf(float f){
  u32 x = __float_as_uint(f);
  x += 0x7fffu + ((x >> 16) & 1u);
  return (u16)(x >> 16);
}
__device__ __forceinline__ float bf2f(u16 u){ return __uint_as_float(((u32)u) << 16); }
__device__ __forceinline__ float qsc(float m, float qmax){ return fmaxf(m / qmax, 1e-8f); }
__device__ __forceinline__ float fq(float x, float s){
  return fminf(fmaxf(rintf(x / s), -127.f), 127.f) * s;
}
__device__ __forceinline__ void blockMaxTo(float* target, float v){
  __shared__ float red[256];
  __syncthreads();
  red[threadIdx.x] = v;
  __syncthreads();
  for (int s = blockDim.x >> 1; s > 0; s >>= 1){
    if ((int)threadIdx.x < s) red[threadIdx.x] = fmaxf(red[threadIdx.x], red[threadIdx.x + s]);
    __syncthreads();
  }
  if (threadIdx.x == 0) atomicMax((int*)target, __float_as_int(red[0]));
}

__global__ void zeromx(float* mx){
  if (threadIdx.x < 64) mx[threadIdx.x] = 0.f;
}

// ---------------- weight quantization (per-output-channel) ----------------
__global__ __launch_bounds__(128) void wquant(
    const float* wq, const float* wk, const float* wv, const float* wproj,
    const float* wfc1, const float* wfc2, const float* wvl, const float* wmid,
    const float* wth1, const float* wth2,
    const float* bq, const float* bk, const float* bv,
    u16* wqkv_b, u16* wproj_b, u16* wfc1_b, u16* wfc2_b,
    float* wvl_q, float* wmid_q, float* wth1_q, float* wth2_q, float* biasqkv)
{
  const int tid = threadIdx.x;
  const int bid = blockIdx.x;
  if (bid == 6416){
    for (int j = tid; j < 1536; j += 128){
      float v = (j < 256) ? bq[j] : ((j < 512) ? bk[j - 256] : bv[j - 512]);
      biasqkv[j] = v;
    }
    return;
  }
  const int rows[10] = {256,256,1024,384,1536,384,1024,1536,8,8};
  int seg = 0, r = bid;
  while (r >= rows[seg]) { r -= rows[seg]; ++seg; }
  int len = 0;
  const float* src = nullptr; u16* db = nullptr; float* df = nullptr;
  switch (seg){
    case 0: len = 384;  src = wq    + r*384;  db = wqkv_b + r*384;        break;
    case 1: len = 384;  src = wk    + r*384;  db = wqkv_b + (256+r)*384;  break;
    case 2: len = 384;  src = wv    + r*384;  db = wqkv_b + (512+r)*384;  break;
    case 3: len = 1024; src = wproj + r*1024; db = wproj_b + r*1024;      break;
    case 4: len = 384;  src = wfc1  + r*384;  db = wfc1_b + r*384;        break;
    case 5: len = 1536; src = wfc2  + r*1536; db = wfc2_b + r*1536;       break;
    case 6: len = 9;    src = wvl   + r*9;    df = wvl_q + r*9;           break;
    case 7: len = 9;    src = wmid  + r*9;    df = wmid_q + r*9;          break;
    case 8: len = 8;    src = wth1  + r*8;    df = wth1_q + r*8;          break;
    default: len = 8;   src = wth2  + r*8;    df = wth2_q + r*8;          break;
  }
  float lm = 0.f;
  for (int j = tid; j < len; j += 128) lm = fmaxf(lm, fabsf(src[j]));
  __shared__ float red[128];
  red[tid] = lm; __syncthreads();
  for (int s = 64; s > 0; s >>= 1){
    if (tid < s) red[tid] = fmaxf(red[tid], red[tid + s]);
    __syncthreads();
  }
  float s = fmaxf(red[0] / 127.f, 1e-8f);
  for (int j = tid; j < len; j += 128){
    float v = fminf(fmaxf(rintf(src[j] / s), -127.f), 127.f) * s;
    if (db) db[j] = f2bf(v); else df[j] = v;
  }
}

// ---------------- x (NCHW) -> xT [m=b*49+p][c] bf16 ----------------
__global__ __launch_bounds__(256) void xpose(const float* __restrict__ x, u16* __restrict__ xT){
  const int b = blockIdx.x;
  __shared__ u16 xb[18816];
  const int tid = threadIdx.x;
  for (int j = tid; j < 18816; j += 256) xb[j] = f2bf(x[(size_t)b*18816 + j]);
  __syncthreads();
  for (int j = tid; j < 18816; j += 256){
    int p = j / 384, c = j - p*384;
    xT[(size_t)b*18816 + j] = xb[c*49 + p];
  }
}

// ---------------- bf16 MFMA GEMM: C[M][N] = A[M][K] * Bt[N][K]^T + bias ----------------
// epi: 0 = absmax, 1 = qkv (3 regions by n0), 2 = relu then posmax. C written as bf16.
__global__ __launch_bounds__(256) void gemm_bt(
    const u16* __restrict__ A, const u16* __restrict__ Bt,
    const float* __restrict__ bias, u16* __restrict__ C,
    float* __restrict__ mx, int N, int K, int epi, int region)
{
  __shared__ __align__(16) u16 As[128*64];
  __shared__ __align__(16) u16 Bs[128*64];
  const int tid = threadIdx.x;
  const int lane = tid & 63, wid = tid >> 6;
  const int n0 = blockIdx.x * 128;
  const int m0 = blockIdx.y * 128;
  const int wr = wid >> 1, wc = wid & 1;
  f32x4 acc[4][4] = {};
  const int nsteps = K >> 6;
  for (int s = 0; s < nsteps; ++s){
    const int k0 = s << 6;
    #pragma unroll
    for (int j = 0; j < 4; ++j){
      int boff = j*4096 + tid*16;
      int row = boff >> 7;
      int ce  = (boff & 127) >> 1;
      uint4 va = *(const uint4*)(A  + (size_t)(m0 + row)*K + k0 + ce);
      uint4 vb = *(const uint4*)(Bt + (size_t)(n0 + row)*K + k0 + ce);
      *(uint4*)&As[boff >> 1] = va;
      *(uint4*)&Bs[boff >> 1] = vb;
    }
    __syncthreads();
    #pragma unroll
    for (int kk = 0; kk < 2; ++kk){
      bf16x8 af[4], bfr[4];
      #pragma unroll
      for (int i = 0; i < 4; ++i){
        int ar = wr*64 + i*16 + (lane & 15);
        af[i]  = *(const bf16x8*)&As[ar*64 + kk*32 + (lane >> 4)*8];
        int br = wc*64 + i*16 + (lane & 15);
        bfr[i] = *(const bf16x8*)&Bs[br*64 + kk*32 + (lane >> 4)*8];
      }
      #pragma unroll
      for (int i = 0; i < 4; ++i){
        #pragma unroll
        for (int j = 0; j < 4; ++j){
          acc[i][j] = __builtin_amdgcn_mfma_f32_16x16x32_bf16(af[i], bfr[j], acc[i][j], 0, 0, 0);
        }
      }
    }
    __syncthreads();
  }
  float lm = 0.f;
  #pragma unroll
  for (int i = 0; i < 4; ++i){
    int rbase = m0 + wr*64 + i*16 + ((lane >> 4) << 2);
    #pragma unroll
    for (int j = 0; j < 4; ++j){
      int col = n0 + wc*64 + j*16 + (lane & 15);
      float bv = bias[col];
      #pragma unroll
      for (int q = 0; q < 4; ++q){
        float v = acc[i][j][q] + bv;
        if (epi == 2) v = fmaxf(v, 0.f);
        C[(size_t)(rbase + q)*N + col] = f2bf(v);
        lm = fmaxf(lm, (epi == 2) ? v : fabsf(v));
      }
    }
  }
  int reg = region;
  if (epi == 1) reg = (n0 < 256) ? 0 : ((n0 < 512) ? 1 : 2);
  blockMaxTo(&mx[reg], lm);
}

// ---------------- depthwise 3x3 local-V absmax only (no output) ----------------
__global__ __launch_bounds__(128) void vlmax(
    const u16* __restrict__ qkv, const float* __restrict__ wv9,
    const float* __restrict__ bvl, float* __restrict__ mx)
{
  const int cc = blockIdx.x, b = blockIdx.y;   // cc = head (128-ch group)
  __shared__ float xin[49*132];
  const float sv = qsc(mx[2], 127.f);
  const int tid = threadIdx.x;
  for (int j = tid; j < 49*128; j += 128){
    int p = j >> 7, c = j & 127;
    xin[p*132 + c] = fq(bf2f(qkv[(size_t)(b*49 + p)*1536 + 512 + cc*128 + c]), sv);
  }
  __syncthreads();
  const int c = tid;
  float w9[9];
  #pragma unroll
  for (int i = 0; i < 9; ++i) w9[i] = wv9[(cc*128 + c)*9 + i];
  const float bb = bvl[cc*128 + c];
  float col[49];
  #pragma unroll
  for (int p = 0; p < 49; ++p) col[p] = xin[p*132 + c];
  float lm = 0.f;
  #pragma unroll
  for (int p = 0; p < 49; ++p){
    const int py = p / 7, px = p % 7;
    float acc = bb;
    #pragma unroll
    for (int dy = 0; dy < 3; ++dy){
      const int yy = py + dy - 1;
      if (yy < 0 || yy > 6) continue;
      #pragma unroll
      for (int dx = 0; dx < 3; ++dx){
        const int xx = px + dx - 1;
        if (xx < 0 || xx > 6) continue;
        acc += col[yy*7 + xx] * w9[dy*3 + dx];
      }
    }
    lm = fmaxf(lm, fabsf(acc));
  }
  blockMaxTo(&mx[3], lm);
}

// ---------------- S = q*k^T*scale + bias ----------------
__global__ __launch_bounds__(256) void attn_qk(
    const u16* __restrict__ qkv, const float* __restrict__ biases,
    const int* __restrict__ idxs, float* __restrict__ S, float* __restrict__ mx)
{
  const int h = blockIdx.x, b = blockIdx.y;
  __shared__ float qs[49*32];
  __shared__ float ks[49*33];
  __shared__ float brow[49];
  const float sq = qsc(mx[0], 127.f), sk = qsc(mx[1], 127.f);
  const int tid = threadIdx.x;
  for (int j = tid; j < 49*32; j += 256){
    int n = j >> 5, kd = j & 31;
    size_t base = (size_t)(b*49 + n)*1536;
    qs[j] = fq(bf2f(qkv[base + h*32 + kd]), sq);
    ks[n*33 + kd] = fq(bf2f(qkv[base + 256 + h*32 + kd]), sk);
  }
  if (tid < 49) brow[tid] = biases[h*49 + tid];
  __syncthreads();
  float lm = 0.f;
  const float scale = 0.17677669529663687f;
  for (int t = tid; t < 2401; t += 256){
    int n = t / 49, m = t - n*49;
    float acc = 0.f;
    #pragma unroll
    for (int kd = 0; kd < 32; ++kd) acc += qs[n*32 + kd] * ks[m*33 + kd];
    float v = acc * scale + brow[idxs[t]];
    S[((size_t)b*8 + h)*2401 + t] = v;
    lm = fmaxf(lm, fabsf(v));
  }
  blockMaxTo(&mx[4], lm);
}

// ---------------- talking head 1 (IN-PLACE on S; no restrict!) ----------------
__global__ __launch_bounds__(256) void th1k(
    const float* S, const float* w1, const float* b1, float* T, float* mx)
{
  const int b = blockIdx.y;
  const int j = blockIdx.x*256 + threadIdx.x;
  __shared__ float wsh[64];
  __shared__ float bsh[8];
  if (threadIdx.x < 64) wsh[threadIdx.x] = w1[threadIdx.x];
  if (threadIdx.x < 8)  bsh[threadIdx.x] = b1[threadIdx.x];
  __syncthreads();
  float lm = 0.f;
  if (j < 2401){
    const float s1 = qsc(mx[4], 127.f);
    float a[8];
    #pragma unroll
    for (int h = 0; h < 8; ++h) a[h] = fq(S[((size_t)b*8 + h)*2401 + j], s1);
    float o8[8];
    #pragma unroll
    for (int o = 0; o < 8; ++o){
      float t = bsh[o];
      #pragma unroll
      for (int h = 0; h < 8; ++h) t += wsh[o*8 + h] * a[h];
      o8[o] = t;
      lm = fmaxf(lm, fabsf(t));
    }
    #pragma unroll
    for (int o = 0; o < 8; ++o) T[((size_t)b*8 + o)*2401 + j] = o8[o];
  }
  blockMaxTo(&mx[5], lm);
}

// ---------------- int softmax (I-BERT) + talking head 2 (IN-PLACE) ----------------
__global__ __launch_bounds__(256) void smth2(
    const float* T, const float* w2, const float* b2, float* U, float* mx)
{
  const int b = blockIdx.x;
  __shared__ float P[19208];
  __shared__ float wsh[64];
  __shared__ float bsh[8];
  const float sa = qsc(mx[5], 127.f);
  const int tid = threadIdx.x;
  if (tid < 64) wsh[tid] = w2[tid];
  if (tid < 8)  bsh[tid] = b2[tid];
  for (int j = tid; j < 19208; j += 256){
    float v = T[(size_t)b*19208 + j];
    P[j] = fminf(fmaxf(rintf(v / sa), -127.f), 127.f);   // integer-valued
  }
  __syncthreads();
  const float x0 = floorf(-0.6931f / sa);
  const float bi = floorf((0.96963238f / 0.35815147f) / sa);
  const float ci = floorf((1.0f / 0.35815147f) / (sa * sa));
  const float Kc = ((0.35815147f * sa) * sa) * (1.f/1073741824.f);
  const float maxv = (ci * 1073741824.f) * Kc;     // analytic global max of exp tensor
  const float se = fmaxf(maxv / 32767.f, 1e-8f);
  const float clampLo = 30.f * x0;
  for (int row = tid; row < 392; row += 256){
    float* pr = &P[row*49];
    float rmax = pr[0];
    for (int m = 1; m < 49; ++m) rmax = fmaxf(rmax, pr[m]);
    float rsum = 0.f;
    for (int m = 0; m < 49; ++m){
      float xi = pr[m] - rmax;
      xi = fmaxf(xi, clampLo);
      float qd = floorf(xi / x0);
      float r = xi - x0*qd;
      float z = (r + bi)*r + ci;
      float ei = floorf(z * exp2f(30.f - qd));
      ei = fmaxf(ei, 0.f);
      float t = ei * Kc;
      float e2 = fminf(fmaxf(rintf(t / se), -32767.f), 32767.f);
      float eint = (e2 * se) / se;
      pr[m] = eint;
      rsum += eint;
    }
    const float factor = floorf(4294967296.f / rsum);
    for (int m = 0; m < 49; ++m){
      pr[m] = floorf((pr[m] * factor) * (1.f/65536.f)) * (1.f/65536.f);
    }
  }
  __syncthreads();
  float lm = 0.f;
  for (int j = tid; j < 19208; j += 256){
    int o = j / 2401, rem = j - o*2401;
    float t = bsh[o];
    #pragma unroll
    for (int h = 0; h < 8; ++h) t += wsh[o*8 + h] * P[h*2401 + rem];
    U[(size_t)b*19208 + j] = t;
    lm = fmaxf(lm, fabsf(t));
  }
  blockMaxTo(&mx[6], lm);
}

// ---------------- out = attn_q @ v_q + fq(dwconv(v_q)) — MFMA version ----------------
// P and V are quantized to INTEGER-valued bf16 (|k|<=127 exact); MFMA accumulates the
// exact integer product; epilogue applies s3*sv once. Depthwise local branch computed
// once into padded LDS (vlq) from integer V, scaled by sv.
__global__ __launch_bounds__(256) void attn_v(
    const u16* __restrict__ qkv, const float* __restrict__ U,
    const float* __restrict__ wv9, const float* __restrict__ bvl,
    u16* __restrict__ av, float* __restrict__ mx)
{
  const int h = blockIdx.x, b = blockIdx.y;
  __shared__ __align__(16) u16 Pb[64*68];     // [n][m] int-valued bf16, stride 68
  __shared__ __align__(16) u16 Vt[128*66];    // [d][m] int-valued bf16, stride 66
  __shared__ float vlq[49*132];               // fq'd local branch, padded
  __shared__ float w9s[1152];
  __shared__ float bvs[128];
  const float s3 = qsc(mx[6], 127.f), sv = qsc(mx[2], 127.f), svl = qsc(mx[3], 127.f);
  const float s3sv = s3 * sv;
  const int tid = threadIdx.x;
  // phase A: zero the padded tiles
  for (int j = tid; j < 64*68; j += 256) Pb[j] = 0;
  for (int j = tid; j < 128*66; j += 256) Vt[j] = 0;
  for (int j = tid; j < 1152; j += 256) w9s[j] = wv9[h*1152 + j];
  if (tid < 128) bvs[tid] = bvl[h*128 + tid];
  __syncthreads();
  // phase B: quantize to integer-valued bf16
  for (int j = tid; j < 2401; j += 256){
    int n = j / 49, m = j - n*49;
    float k = fminf(fmaxf(rintf(U[((size_t)b*8 + h)*2401 + j] / s3), -127.f), 127.f);
    Pb[n*68 + m] = f2bf(k);
  }
  for (int j = tid; j < 6272; j += 256){
    int m = j >> 7, d = j & 127;
    float k = fminf(fmaxf(rintf(bf2f(qkv[(size_t)(b*49 + m)*1536 + 512 + h*128 + d]) / sv), -127.f), 127.f);
    Vt[d*66 + m] = f2bf(k);
  }
  __syncthreads();
  // phase C: depthwise 3x3 local branch from integer V (acc = bvl + sv * int_conv)
  for (int j = tid; j < 6272; j += 256){
    int n = j >> 7, c = j & 127;
    const int py = n / 7, px = n % 7;
    float acc = 0.f;
    #pragma unroll
    for (int dy = 0; dy < 3; ++dy){
      const int yy = py + dy - 1;
      if (yy < 0 || yy > 6) continue;
      #pragma unroll
      for (int dx = 0; dx < 3; ++dx){
        const int xx = px + dx - 1;
        if (xx < 0 || xx > 6) continue;
        acc += bf2f(Vt[c*66 + yy*7 + xx]) * w9s[c*9 + dy*3 + dx];
      }
    }
    vlq[n*132 + c] = fq(sv*acc + bvs[c], svl);
  }
  __syncthreads();
  // phase D: MFMA  (M=64 rows, N=32 cols per wave, K=64)
  const int lane = tid & 63, wid = tid >> 6;
  const int col0 = wid * 32;
  f32x4 acc[4][2] = {};
  #pragma unroll
  for (int kk = 0; kk < 2; ++kk){
    bf16x8 af[4], bfr[2];
    #pragma unroll
    for (int i = 0; i < 4; ++i)
      af[i] = *(const bf16x8*)&Pb[(i*16 + (lane & 15))*68 + kk*32 + (lane >> 4)*8];
    #pragma unroll
    for (int j = 0; j < 2; ++j)
      bfr[j] = *(const bf16x8*)&Vt[(col0 + j*16 + (lane & 15))*66 + kk*32 + (lane >> 4)*8];
    #pragma unroll
    for (int i = 0; i < 4; ++i)
      #pragma unroll
      for (int j = 0; j < 2; ++j)
        acc[i][j] = __builtin_amdgcn_mfma_f32_16x16x32_bf16(af[i], bfr[j], acc[i][j], 0, 0, 0);
  }
  // phase E: epilogue — scale, add local branch, write, track maxima
  float lm = 0.f, lmp = 0.f;
  #pragma unroll
  for (int i = 0; i < 4; ++i){
    #pragma unroll
    for (int q = 0; q < 4; ++q){
      int row = i*16 + (lane >> 4)*4 + q;
      if (row < 49){
        #pragma unroll
        for (int j = 0; j < 2; ++j){
          int col = col0 + j*16 + (lane & 15);
          float v = acc[i][j][q] * s3sv + vlq[row*132 + col];
          av[(size_t)(b*49 + row)*1024 + h*128 + col] = f2bf(v);
          lm = fmaxf(lm, fabsf(v));
          lmp = fmaxf(lmp, v);
        }
      }
    }
  }
  blockMaxTo(&mx[7], lm);
  blockMaxTo(&mx[8], lmp);
}

// ---------------- av -> quant(av_res) -> relu -> quant(proj_in) (IN-PLACE) ----------------
__global__ void av2bf(const u16* av, u16* ap, const float* mx){
  const float sres = qsc(mx[7], 127.f);
  const float posq = fq(mx[8], sres);
  const float spi = fmaxf(posq / 127.f, 1e-8f);
  const size_t n = (size_t)25088*1024;
  for (size_t i = (size_t)blockIdx.x*blockDim.x + threadIdx.x; i < n; i += (size_t)gridDim.x*blockDim.x){
    float r1 = fq(bf2f(av[i]), sres);
    float r2 = fmaxf(r1, 0.f);
    ap[i] = f2bf(fq(r2, spi));
  }
}

// ---------------- y1 = x + ls1*quant(proj), absmax ----------------
__global__ __launch_bounds__(256) void res1max(
    const float* __restrict__ x, const u16* __restrict__ praw,
    const float* __restrict__ ls1, float* __restrict__ y1, float* __restrict__ mx)
{
  const int b = blockIdx.x;
  __shared__ float xs[18816];
  __shared__ float lss[384];
  const float sp = qsc(mx[9], 127.f);
  const int tid = threadIdx.x;
  for (int j = tid; j < 18816; j += 256) xs[j] = x[(size_t)b*18816 + j];
  for (int j = tid; j < 384; j += 256) lss[j] = ls1[j];
  __syncthreads();
  float lm = 0.f;
  for (int j = tid; j < 18816; j += 256){
    int p = j / 384, c = j - p*384;
    float y = xs[c*49 + p] + lss[c] * fq(bf2f(praw[(size_t)b*18816 + j]), sp);
    y1[(size_t)b*18816 + j] = y;
    lm = fmaxf(lm, fabsf(y));
  }
  blockMaxTo(&mx[10], lm);
}

// ---------------- x1 = quant(y1): fp32 (in d_out) + bf16 copies ----------------
__global__ void qx1(const float* __restrict__ y1, float* __restrict__ x1f, u16* __restrict__ x1b,
                    const float* __restrict__ mx){
  const float s = qsc(mx[10], 127.f);
  const size_t n = (size_t)9633792;
  for (size_t i = (size_t)blockIdx.x*blockDim.x + threadIdx.x; i < n; i += (size_t)gridDim.x*blockDim.x){
    float v = fq(y1[i], s);
    x1f[i] = v;
    x1b[i] = f2bf(v);
  }
}

// ---------------- depthwise 3x3 (mid conv) + relu (IN-PLACE on h1) ----------------
__global__ __launch_bounds__(128) void dw_mid(
    const u16* h1, const float* wm9, const float* bmid, u16* m1, float* mx)
{
  const int cc = blockIdx.x, b = blockIdx.y;
  __shared__ float xin[49*132];
  const float sh = qsc(mx[11], 127.f);
  const int tid = threadIdx.x;
  for (int j = tid; j < 49*128; j += 128){
    int p = j >> 7, c = j & 127;
    xin[p*132 + c] = fq(bf2f(h1[(size_t)(b*49 + p)*1536 + cc*128 + c]), sh);
  }
  __syncthreads();
  const int c = tid;
  float w9[9];
  #pragma unroll
  for (int i = 0; i < 9; ++i) w9[i] = wm9[(cc*128 + c)*9 + i];
  const float bb = bmid[cc*128 + c];
  float col[49];
  #pragma unroll
  for (int p = 0; p < 49; ++p) col[p] = xin[p*132 + c];
  float lm = 0.f;
  #pragma unroll
  for (int p = 0; p < 49; ++p){
    const int py = p / 7, px = p % 7;
    float acc = bb;
    #pragma unroll
    for (int dy = 0; dy < 3; ++dy){
      const int yy = py + dy - 1;
      if (yy < 0 || yy > 6) continue;
      #pragma unroll
      for (int dx = 0; dx < 3; ++dx){
        const int xx = px + dx - 1;
        if (xx < 0 || xx > 6) continue;
        acc += col[yy*7 + xx] * w9[dy*3 + dx];
      }
    }
    acc = fmaxf(acc, 0.f);
    m1[(size_t)(b*49 + p)*1536 + cc*128 + c] = f2bf(acc);
    lm = fmaxf(lm, acc);
  }
  blockMaxTo(&mx[12], lm);
}

// ---------------- mid -> quant -> bf16 (IN-PLACE) ----------------
__global__ void mid2bf(const u16* m1, u16* mb, const float* mx){
  const float s = qsc(mx[12], 127.f);
  const size_t n = (size_t)25088*1536;
  for (size_t i = (size_t)blockIdx.x*blockDim.x + threadIdx.x; i < n; i += (size_t)gridDim.x*blockDim.x){
    mb[i] = f2bf(fq(bf2f(m1[i]), s));
  }
}

// ---------------- y2 = x1 + ls2*quant(fc2), absmax ----------------
__global__ __launch_bounds__(256) void res2max(
    const float* __restrict__ x1f, const u16* __restrict__ f2,
    const float* __restrict__ ls2, float* __restrict__ y2, float* __restrict__ mx)
{
  const float s = qsc(mx[13], 127.f);
  float lm = 0.f;
  const size_t n = (size_t)9633792;
  for (size_t i = (size_t)blockIdx.x*blockDim.x + threadIdx.x; i < n; i += (size_t)gridDim.x*blockDim.x){
    int c = (int)(i % 384);
    float y = x1f[i] + ls2[c] * fq(bf2f(f2[i]), s);
    y2[i] = y;
    lm = fmaxf(lm, fabsf(y));
  }
  blockMaxTo(&mx[14], lm);
}

// ---------------- out2 = quant(y2), transpose to NCHW, plus out_sf ----------------
__global__ __launch_bounds__(256) void finalout(
    const float* __restrict__ y2, float* __restrict__ out, const float* __restrict__ mx)
{
  const int b = blockIdx.x;
  __shared__ float os[18816];
  const float s = qsc(mx[14], 127.f);
  const int tid = threadIdx.x;
  for (int j = tid; j < 18816; j += 256){
    int p = j / 384, c = j - p*384;
    os[c*49 + p] = fq(y2[(size_t)b*18816 + j], s);
  }
  __syncthreads();
  for (int j = tid; j < 18816; j += 256) out[(size_t)b*18816 + j] = os[j];
  if (b == 0 && tid == 0) out[9633792] = s;
}

extern "C" void kernel_launch(void* const* d_in, const int* in_sizes, int n_in,
                              void* d_out, int out_size, void* d_ws, size_t ws_size,
                              hipStream_t stream)
{
  (void)in_sizes; (void)n_in; (void)out_size; (void)ws_size;
  const float* x    = (const float*)d_in[0];
  const float* wq   = (const float*)d_in[2];
  const float* bq   = (const float*)d_in[3];
  const float* wk   = (const float*)d_in[4];
  const float* bk   = (const float*)d_in[5];
  const float* wv   = (const float*)d_in[6];
  const float* bv   = (const float*)d_in[7];
  const float* wvl  = (const float*)d_in[8];
  const float* bvl  = (const float*)d_in[9];
  const float* ab   = (const float*)d_in[10];
  const float* wth1 = (const float*)d_in[11];
  const float* bth1 = (const float*)d_in[12];
  const float* wth2 = (const float*)d_in[13];
  const float* bth2 = (const float*)d_in[14];
  const float* wproj= (const float*)d_in[15];
  const float* bproj= (const float*)d_in[16];
  const float* wfc1 = (const float*)d_in[17];
  const float* bfc1 = (const float*)d_in[18];
  const float* wmid = (const float*)d_in[19];
  const float* bmid = (const float*)d_in[20];
  const float* wfc2 = (const float*)d_in[21];
  const float* bfc2 = (const float*)d_in[22];
  const float* ls1  = (const float*)d_in[23];
  const float* ls2  = (const float*)d_in[24];
  const int*   idxs = (const int*)d_in[25];
  float* out = (float*)d_out;

  // ---- workspace layout (total 191,480,576 B ~= 183 MiB) ----
  char* w = (char*)d_ws;
  float* mx      = (float*)(w + 0);            // 256 B
  float* biasqkv = (float*)(w + 256);          // 6 KB
  u16* wqkv_b    = (u16*)(w + 6400);           // 1.18 MB
  u16* wproj_b   = (u16*)(w + 1186048);        // 786 KB
  u16* wfc1_b    = (u16*)(w + 1972480);        // 1.18 MB
  u16* wfc2_b    = (u16*)(w + 3152128);        // 1.18 MB
  float* wvl_q   = (float*)(w + 4331776);      // 36.9 KB
  float* wmid_q  = (float*)(w + 4368640);      // 55.3 KB
  float* wth1_q  = (float*)(w + 4423936);      // 256 B
  float* wth2_q  = (float*)(w + 4424192);      // 256 B
  // W1 (19.27 MB): xT -> praw -> x1b -> f2raw  (disjoint lifetimes)
  u16* xT    = (u16*)(w + 4424448);
  u16* praw  = xT;
  u16* x1b   = xT;
  u16* f2raw = xT;
  // W2 (77.07 MB): qkv -> h1 (dw_mid & mid2bf run in place)
  u16* qkv = (u16*)(w + 23692032);
  u16* h1  = qkv;
  // W4 (51.38 MB): avb (av2bf in place; then proj input)
  u16* avb = (u16*)(w + 100762368);
  // W5 (39.34 MB): S (th1k/smth2 in place) -> y1 -> y2
  float* S  = (float*)(w + 152142592);
  float* y1 = S;
  float* y2 = S;
  // x1f (38.54 MB fp32) lives in d_out; overwritten by finalout at the end
  float* x1f = out;

  zeromx<<<1, 64, 0, stream>>>(mx);
  wquant<<<6417, 128, 0, stream>>>(wq, wk, wv, wproj, wfc1, wfc2, wvl, wmid, wth1, wth2,
                                   bq, bk, bv,
                                   wqkv_b, wproj_b, wfc1_b, wfc2_b,
                                   wvl_q, wmid_q, wth1_q, wth2_q, biasqkv);
  xpose<<<512, 256, 0, stream>>>(x, xT);
  gemm_bt<<<dim3(12, 196), 256, 0, stream>>>(xT, wqkv_b, biasqkv, qkv, mx, 1536, 384, 1, 0);
  attn_qk<<<dim3(8, 512), 256, 0, stream>>>(qkv, ab, idxs, S, mx);
  vlmax<<<dim3(8, 512), 128, 0, stream>>>(qkv, wvl_q, bvl, mx);
  th1k<<<dim3(10, 512), 256, 0, stream>>>(S, wth1_q, bth1, S, mx);
  smth2<<<512, 256, 0, stream>>>(S, wth2_q, bth2, S, mx);
  attn_v<<<dim3(8, 512), 256, 0, stream>>>(qkv, S, wvl_q, bvl, avb, mx);
  av2bf<<<2048, 256, 0, stream>>>(avb, avb, mx);
  gemm_bt<<<dim3(3, 196), 256, 0, stream>>>(avb, wproj_b, bproj, praw, mx, 384, 1024, 0, 9);
  res1max<<<512, 256, 0, stream>>>(x, praw, ls1, y1, mx);
  qx1<<<2048, 256, 0, stream>>>(y1, x1f, x1b, mx);
  gemm_bt<<<dim3(12, 196), 256, 0, stream>>>(x1b, wfc1_b, bfc1, h1, mx, 1536, 384, 2, 11);
  dw_mid<<<dim3(12, 512), 128, 0, stream>>>(h1, wmid_q, bmid, h1, mx);
  mid2bf<<<2048, 256, 0, stream>>>(h1, h1, mx);
  gemm_bt<<<dim3(3, 196), 256, 0, stream>>>(h1, wfc2_b, bfc2, f2raw, mx, 384, 1536, 0, 13);
  res2max<<<2048, 256, 0, stream>>>(x1f, f2raw, ls2, y2, mx);
  finalout<<<512, 256, 0, stream>>>(y2, out, mx);
}

// Round 4
// 899.487 us; speedup vs baseline: 1.4450x; 1.1356x over previous
//
#include <hip/hip_runtime.h>

typedef unsigned short u16;
typedef unsigned int u32;
typedef float f32x4 __attribute__((ext_vector_type(4)));
typedef short bf16x8 __attribute__((ext_vector_type(8)));
typedef short s16x4 __attribute__((ext_vector_type(4)));

// ---- geometry ----
// B=512, DIM=384, RES=7, N=49, NH=8, KD=32, D=128, DH=1024, NHKD=256, HID=1536
// M = B*49 = 25088
// max-scalar table (ws offset 0):
// 0 Mq 1 Mk 2 Mv 3 Mvl 4 Mpre_th1 5 Mattn 6 Mpostsm 7 Mres_abs 8 Mres_pos
// 9 Mproj 10 Mx1 11 Mh1(relu) 12 Mmid(relu) 13 Mfc2 14 Mfinal

__device__ __forceinline__ u16 f2bf(float f){
  u32 x = __float_as_uint(f);
  x += 0x7fffu + ((x >> 16) & 1u);
  return (u16)(x >> 16);
}
__device__ __forceinline__ float bf2f(u16 u){ return __uint_as_float(((u32)u) << 16); }
__device__ __forceinline__ float qsc(float m, float qmax){ return fmaxf(m / qmax, 1e-8f); }
// exact-division fake quant (used on the residual spine)
__device__ __forceinline__ float fq(float x, float s){
  return fminf(fmaxf(rintf(x / s), -127.f), 127.f) * s;
}
// reciprocal-mul fake quant (ls1/ls2-insulated paths only)
__device__ __forceinline__ float fqi(float x, float s, float inv){
  return fminf(fmaxf(rintf(x * inv), -127.f), 127.f) * s;
}
__device__ __forceinline__ void blockMaxTo(float* target, float v){
  __shared__ float red[256];
  __syncthreads();
  red[threadIdx.x] = v;
  __syncthreads();
  for (int s = blockDim.x >> 1; s > 0; s >>= 1){
    if ((int)threadIdx.x < s) red[threadIdx.x] = fmaxf(red[threadIdx.x], red[threadIdx.x + s]);
    __syncthreads();
  }
  if (threadIdx.x == 0) atomicMax((int*)target, __float_as_int(red[0]));
}

__device__ __forceinline__ void gload16(const void* g, void* l){
  __builtin_amdgcn_global_load_lds((const __attribute__((address_space(1))) u32*)g,
                                   (__attribute__((address_space(3))) u32*)l, 16, 0, 0);
}

__global__ void zeromx(float* mx){
  if (threadIdx.x < 64) mx[threadIdx.x] = 0.f;
}

// ---------------- weight quantization (per-output-channel) ----------------
__global__ __launch_bounds__(128) void wquant(
    const float* wq, const float* wk, const float* wv, const float* wproj,
    const float* wfc1, const float* wfc2, const float* wvl, const float* wmid,
    const float* wth1, const float* wth2,
    const float* bq, const float* bk, const float* bv,
    u16* wqkv_b, u16* wproj_b, u16* wfc1_b, u16* wfc2_b,
    float* wvl_q, float* wmid_q, float* wth1_q, float* wth2_q, float* biasqkv)
{
  const int tid = threadIdx.x;
  const int bid = blockIdx.x;
  if (bid == 6416){
    for (int j = tid; j < 1536; j += 128){
      float v = (j < 256) ? bq[j] : ((j < 512) ? bk[j - 256] : bv[j - 512]);
      biasqkv[j] = v;
    }
    return;
  }
  const int rows[10] = {256,256,1024,384,1536,384,1024,1536,8,8};
  int seg = 0, r = bid;
  while (r >= rows[seg]) { r -= rows[seg]; ++seg; }
  int len = 0;
  const float* src = nullptr; u16* db = nullptr; float* df = nullptr;
  switch (seg){
    case 0: len = 384;  src = wq    + r*384;  db = wqkv_b + r*384;        break;
    case 1: len = 384;  src = wk    + r*384;  db = wqkv_b + (256+r)*384;  break;
    case 2: len = 384;  src = wv    + r*384;  db = wqkv_b + (512+r)*384;  break;
    case 3: len = 1024; src = wproj + r*1024; db = wproj_b + r*1024;      break;
    case 4: len = 384;  src = wfc1  + r*384;  db = wfc1_b + r*384;        break;
    case 5: len = 1536; src = wfc2  + r*1536; db = wfc2_b + r*1536;       break;
    case 6: len = 9;    src = wvl   + r*9;    df = wvl_q + r*9;           break;
    case 7: len = 9;    src = wmid  + r*9;    df = wmid_q + r*9;          break;
    case 8: len = 8;    src = wth1  + r*8;    df = wth1_q + r*8;          break;
    default: len = 8;   src = wth2  + r*8;    df = wth2_q + r*8;          break;
  }
  float lm = 0.f;
  for (int j = tid; j < len; j += 128) lm = fmaxf(lm, fabsf(src[j]));
  __shared__ float red[128];
  red[tid] = lm; __syncthreads();
  for (int s = 64; s > 0; s >>= 1){
    if (tid < s) red[tid] = fmaxf(red[tid], red[tid + s]);
    __syncthreads();
  }
  float s = fmaxf(red[0] / 127.f, 1e-8f);
  for (int j = tid; j < len; j += 128){
    float v = fminf(fmaxf(rintf(src[j] / s), -127.f), 127.f) * s;
    if (db) db[j] = f2bf(v); else df[j] = v;
  }
}

// ---------------- x (NCHW) -> xT [m=b*49+p][c] bf16 ----------------
__global__ __launch_bounds__(256) void xpose(const float* __restrict__ x, u16* __restrict__ xT){
  const int b = blockIdx.x;
  __shared__ u16 xb[18816];
  const int tid = threadIdx.x;
  for (int jj = tid; jj < 4704; jj += 256){
    const float4 v = *(const float4*)&x[(size_t)b*18816 + jj*4];
    xb[jj*4+0] = f2bf(v.x); xb[jj*4+1] = f2bf(v.y);
    xb[jj*4+2] = f2bf(v.z); xb[jj*4+3] = f2bf(v.w);
  }
  __syncthreads();
  for (int jj = tid; jj < 4704; jj += 256){
    int j = jj*4, p = j / 384, c = j - p*384;
    s16x4 o;
    #pragma unroll
    for (int u = 0; u < 4; ++u) o[u] = (short)xb[(c+u)*49 + p];
    *(s16x4*)&xT[(size_t)b*18816 + j] = o;
  }
}

// ---------------- bf16 MFMA GEMM: C[M][N] = A[M][K] * Bt[N][K]^T + bias ----------------
// Staging via global_load_lds width-16 (direct HBM->LDS, no VGPR round-trip).
// epi: 0 = absmax, 1 = qkv (3 regions by n0), 2 = relu then posmax. C written as bf16.
__global__ __launch_bounds__(256) void gemm_bt(
    const u16* __restrict__ A, const u16* __restrict__ Bt,
    const float* __restrict__ bias, u16* __restrict__ C,
    float* __restrict__ mx, int N, int K, int epi, int region)
{
  __shared__ __align__(16) u16 As[128*64];
  __shared__ __align__(16) u16 Bs[128*64];
  const int tid = threadIdx.x;
  const int lane = tid & 63, wid = tid >> 6;
  const int n0 = blockIdx.x * 128;
  const int m0 = blockIdx.y * 128;
  const int wr = wid >> 1, wc = wid & 1;
  f32x4 acc[4][4] = {};
  const int nsteps = K >> 6;
  for (int s = 0; s < nsteps; ++s){
    const int k0 = s << 6;
    #pragma unroll
    for (int j = 0; j < 4; ++j){
      int boff = j*4096 + tid*16;      // byte offset into As/Bs (wave-linear)
      int row = boff >> 7;
      int ce  = (boff & 127) >> 1;
      gload16(A  + (size_t)(m0 + row)*K + k0 + ce, (char*)As + boff);
      gload16(Bt + (size_t)(n0 + row)*K + k0 + ce, (char*)Bs + boff);
    }
    __syncthreads();
    #pragma unroll
    for (int kk = 0; kk < 2; ++kk){
      bf16x8 af[4], bfr[4];
      #pragma unroll
      for (int i = 0; i < 4; ++i){
        int ar = wr*64 + i*16 + (lane & 15);
        af[i]  = *(const bf16x8*)&As[ar*64 + kk*32 + (lane >> 4)*8];
        int br = wc*64 + i*16 + (lane & 15);
        bfr[i] = *(const bf16x8*)&Bs[br*64 + kk*32 + (lane >> 4)*8];
      }
      #pragma unroll
      for (int i = 0; i < 4; ++i){
        #pragma unroll
        for (int j = 0; j < 4; ++j){
          acc[i][j] = __builtin_amdgcn_mfma_f32_16x16x32_bf16(af[i], bfr[j], acc[i][j], 0, 0, 0);
        }
      }
    }
    __syncthreads();
  }
  float lm = 0.f;
  #pragma unroll
  for (int i = 0; i < 4; ++i){
    int rbase = m0 + wr*64 + i*16 + ((lane >> 4) << 2);
    #pragma unroll
    for (int j = 0; j < 4; ++j){
      int col = n0 + wc*64 + j*16 + (lane & 15);
      float bv = bias[col];
      #pragma unroll
      for (int q = 0; q < 4; ++q){
        float v = acc[i][j][q] + bv;
        if (epi == 2) v = fmaxf(v, 0.f);
        C[(size_t)(rbase + q)*N + col] = f2bf(v);
        lm = fmaxf(lm, (epi == 2) ? v : fabsf(v));
      }
    }
  }
  int reg = region;
  if (epi == 1) reg = (n0 < 256) ? 0 : ((n0 < 512) ? 1 : 2);
  blockMaxTo(&mx[reg], lm);
}

// ---------------- depthwise 3x3 local-V absmax only (no output) ----------------
__global__ __launch_bounds__(128) void vlmax(
    const u16* __restrict__ qkv, const float* __restrict__ wv9,
    const float* __restrict__ bvl, float* __restrict__ mx)
{
  const int cc = blockIdx.x, b = blockIdx.y;   // cc = head (128-ch group)
  __shared__ float xin[49*132];
  const float sv = qsc(mx[2], 127.f);
  const float iv = 1.f / sv;
  const int tid = threadIdx.x;
  for (int j = tid; j < 784; j += 128){
    int p = j >> 4, dg = j & 15;
    const bf16x8 vv = *(const bf16x8*)&qkv[(size_t)(b*49 + p)*1536 + 512 + cc*128 + dg*8];
    #pragma unroll
    for (int u = 0; u < 8; ++u)
      xin[p*132 + dg*8 + u] = fqi(bf2f((u16)vv[u]), sv, iv);
  }
  __syncthreads();
  const int c = tid;
  float w9[9];
  #pragma unroll
  for (int i = 0; i < 9; ++i) w9[i] = wv9[(cc*128 + c)*9 + i];
  const float bb = bvl[cc*128 + c];
  float col[49];
  #pragma unroll
  for (int p = 0; p < 49; ++p) col[p] = xin[p*132 + c];
  float lm = 0.f;
  #pragma unroll
  for (int p = 0; p < 49; ++p){
    const int py = p / 7, px = p % 7;
    float acc = bb;
    #pragma unroll
    for (int dy = 0; dy < 3; ++dy){
      const int yy = py + dy - 1;
      if (yy < 0 || yy > 6) continue;
      #pragma unroll
      for (int dx = 0; dx < 3; ++dx){
        const int xx = px + dx - 1;
        if (xx < 0 || xx > 6) continue;
        acc += col[yy*7 + xx] * w9[dy*3 + dx];
      }
    }
    lm = fmaxf(lm, fabsf(acc));
  }
  blockMaxTo(&mx[3], lm);
}

// ---------------- S = q*k^T*scale + bias ----------------
__global__ __launch_bounds__(256) void attn_qk(
    const u16* __restrict__ qkv, const float* __restrict__ biases,
    const int* __restrict__ idxs, float* __restrict__ S, float* __restrict__ mx)
{
  const int h = blockIdx.x, b = blockIdx.y;
  __shared__ float qs[49*32];
  __shared__ float ks[49*33];
  __shared__ float brow[49];
  const float sq = qsc(mx[0], 127.f), sk = qsc(mx[1], 127.f);
  const float iq = 1.f/sq, ik = 1.f/sk;
  const int tid = threadIdx.x;
  for (int j = tid; j < 196; j += 256){
    int n = j >> 2, d0 = (j & 3)*8;
    size_t base = (size_t)(b*49 + n)*1536;
    const bf16x8 qv = *(const bf16x8*)&qkv[base + h*32 + d0];
    const bf16x8 kv = *(const bf16x8*)&qkv[base + 256 + h*32 + d0];
    #pragma unroll
    for (int u = 0; u < 8; ++u){
      qs[n*32 + d0 + u] = fqi(bf2f((u16)qv[u]), sq, iq);
      ks[n*33 + d0 + u] = fqi(bf2f((u16)kv[u]), sk, ik);
    }
  }
  if (tid < 49) brow[tid] = biases[h*49 + tid];
  __syncthreads();
  float lm = 0.f;
  const float scale = 0.17677669529663687f;
  for (int t = tid; t < 2401; t += 256){
    int n = t / 49, m = t - n*49;
    float acc = 0.f;
    #pragma unroll
    for (int kd = 0; kd < 32; ++kd) acc += qs[n*32 + kd] * ks[m*33 + kd];
    float v = acc * scale + brow[idxs[t]];
    S[((size_t)b*8 + h)*2401 + t] = v;
    lm = fmaxf(lm, fabsf(v));
  }
  blockMaxTo(&mx[4], lm);
}

// ---------------- talking head 1 (IN-PLACE on S; no restrict!) ----------------
__global__ __launch_bounds__(256) void th1k(
    const float* S, const float* w1, const float* b1, float* T, float* mx)
{
  const int b = blockIdx.y;
  const int j = blockIdx.x*256 + threadIdx.x;
  __shared__ float wsh[64];
  __shared__ float bsh[8];
  if (threadIdx.x < 64) wsh[threadIdx.x] = w1[threadIdx.x];
  if (threadIdx.x < 8)  bsh[threadIdx.x] = b1[threadIdx.x];
  __syncthreads();
  float lm = 0.f;
  if (j < 2401){
    const float s1 = qsc(mx[4], 127.f);
    const float i1 = 1.f/s1;
    float a[8];
    #pragma unroll
    for (int h = 0; h < 8; ++h) a[h] = fqi(S[((size_t)b*8 + h)*2401 + j], s1, i1);
    float o8[8];
    #pragma unroll
    for (int o = 0; o < 8; ++o){
      float t = bsh[o];
      #pragma unroll
      for (int h = 0; h < 8; ++h) t += wsh[o*8 + h] * a[h];
      o8[o] = t;
      lm = fmaxf(lm, fabsf(t));
    }
    #pragma unroll
    for (int o = 0; o < 8; ++o) T[((size_t)b*8 + o)*2401 + j] = o8[o];
  }
  blockMaxTo(&mx[5], lm);
}

// ---------------- int softmax (I-BERT) + talking head 2 (IN-PLACE) ----------------
__global__ __launch_bounds__(256) void smth2(
    const float* T, const float* w2, const float* b2, float* U, float* mx)
{
  const int b = blockIdx.x;
  __shared__ float P[19208];
  __shared__ float wsh[64];
  __shared__ float bsh[8];
  const float sa = qsc(mx[5], 127.f);
  const int tid = threadIdx.x;
  if (tid < 64) wsh[tid] = w2[tid];
  if (tid < 8)  bsh[tid] = b2[tid];
  for (int j = tid; j < 19208; j += 256){
    float v = T[(size_t)b*19208 + j];
    P[j] = fminf(fmaxf(rintf(v / sa), -127.f), 127.f);   // integer-valued
  }
  __syncthreads();
  const float x0 = floorf(-0.6931f / sa);
  const float bi = floorf((0.96963238f / 0.35815147f) / sa);
  const float ci = floorf((1.0f / 0.35815147f) / (sa * sa));
  const float Kc = ((0.35815147f * sa) * sa) * (1.f/1073741824.f);
  const float maxv = (ci * 1073741824.f) * Kc;     // analytic global max of exp tensor
  const float se = fmaxf(maxv / 32767.f, 1e-8f);
  const float clampLo = 30.f * x0;
  for (int row = tid; row < 392; row += 256){
    float* pr = &P[row*49];
    float rmax = pr[0];
    for (int m = 1; m < 49; ++m) rmax = fmaxf(rmax, pr[m]);
    float rsum = 0.f;
    for (int m = 0; m < 49; ++m){
      float xi = pr[m] - rmax;
      xi = fmaxf(xi, clampLo);
      float qd = floorf(xi / x0);
      float r = xi - x0*qd;
      float z = (r + bi)*r + ci;
      float ei = floorf(z * exp2f(30.f - qd));
      ei = fmaxf(ei, 0.f);
      float t = ei * Kc;
      float e2 = fminf(fmaxf(rintf(t / se), -32767.f), 32767.f);
      float eint = (e2 * se) / se;
      pr[m] = eint;
      rsum += eint;
    }
    const float factor = floorf(4294967296.f / rsum);
    for (int m = 0; m < 49; ++m){
      pr[m] = floorf((pr[m] * factor) * (1.f/65536.f)) * (1.f/65536.f);
    }
  }
  __syncthreads();
  float lm = 0.f;
  for (int j = tid; j < 19208; j += 256){
    int o = j / 2401, rem = j - o*2401;
    float t = bsh[o];
    #pragma unroll
    for (int h = 0; h < 8; ++h) t += wsh[o*8 + h] * P[h*2401 + rem];
    U[(size_t)b*19208 + j] = t;
    lm = fmaxf(lm, fabsf(t));
  }
  blockMaxTo(&mx[6], lm);
}

// ---------------- out = attn_q @ v_q + fq(dwconv(v_q)) — MFMA version ----------------
// P and V are quantized to INTEGER-valued bf16 (|k|<=127 exact); MFMA accumulates the
// exact integer product; epilogue applies s3*sv once. Local 3x3 branch stored bf16.
__global__ __launch_bounds__(256) void attn_v(
    const u16* __restrict__ qkv, const float* __restrict__ U,
    const float* __restrict__ wv9, const float* __restrict__ bvl,
    u16* __restrict__ av, float* __restrict__ mx)
{
  const int h = blockIdx.x, b = blockIdx.y;
  __shared__ __align__(16) u16 Pb[64*68];     // [n][m] int-valued bf16, stride 68
  __shared__ __align__(16) u16 Vt[128*66];    // [d][m] int-valued bf16, stride 66
  __shared__ u16 vlq[49*132];                 // fq'd local branch, bf16, padded
  __shared__ float w9s[1152];
  __shared__ float bvs[128];
  const float s3 = qsc(mx[6], 127.f), sv = qsc(mx[2], 127.f), svl = qsc(mx[3], 127.f);
  const float i3 = 1.f/s3, iv = 1.f/sv, il = 1.f/svl;
  const float s3sv = s3 * sv;
  const int tid = threadIdx.x;
  // phase A: zero the padded tiles
  for (int j = tid; j < 64*68; j += 256) Pb[j] = 0;
  for (int j = tid; j < 128*66; j += 256) Vt[j] = 0;
  for (int j = tid; j < 1152; j += 256) w9s[j] = wv9[h*1152 + j];
  if (tid < 128) bvs[tid] = bvl[h*128 + tid];
  __syncthreads();
  // phase B: quantize to integer-valued bf16
  for (int j = tid; j < 2401; j += 256){
    int n = j / 49, m = j - n*49;
    float k = fminf(fmaxf(rintf(U[((size_t)b*8 + h)*2401 + j] * i3), -127.f), 127.f);
    Pb[n*68 + m] = f2bf(k);
  }
  for (int j = tid; j < 784; j += 256){
    int m = j >> 4, dg = j & 15;
    const bf16x8 vv = *(const bf16x8*)&qkv[(size_t)(b*49 + m)*1536 + 512 + h*128 + dg*8];
    #pragma unroll
    for (int u = 0; u < 8; ++u){
      float k = fminf(fmaxf(rintf(bf2f((u16)vv[u]) * iv), -127.f), 127.f);
      Vt[(dg*8 + u)*66 + m] = f2bf(k);
    }
  }
  __syncthreads();
  // phase C: depthwise 3x3 local branch from integer V (acc = bvl + sv * int_conv)
  for (int j = tid; j < 6272; j += 256){
    int n = j >> 7, c = j & 127;
    const int py = n / 7, px = n % 7;
    float acc = 0.f;
    #pragma unroll
    for (int dy = 0; dy < 3; ++dy){
      const int yy = py + dy - 1;
      if (yy < 0 || yy > 6) continue;
      #pragma unroll
      for (int dx = 0; dx < 3; ++dx){
        const int xx = px + dx - 1;
        if (xx < 0 || xx > 6) continue;
        acc += bf2f(Vt[c*66 + yy*7 + xx]) * w9s[c*9 + dy*3 + dx];
      }
    }
    vlq[n*132 + c] = f2bf(fqi(sv*acc + bvs[c], svl, il));
  }
  __syncthreads();
  // phase D: MFMA  (M=64 rows, N=32 cols per wave, K=64)
  const int lane = tid & 63, wid = tid >> 6;
  const int col0 = wid * 32;
  f32x4 acc[4][2] = {};
  #pragma unroll
  for (int kk = 0; kk < 2; ++kk){
    bf16x8 af[4], bfr[2];
    #pragma unroll
    for (int i = 0; i < 4; ++i)
      af[i] = *(const bf16x8*)&Pb[(i*16 + (lane & 15))*68 + kk*32 + (lane >> 4)*8];
    #pragma unroll
    for (int j = 0; j < 2; ++j)
      bfr[j] = *(const bf16x8*)&Vt[(col0 + j*16 + (lane & 15))*66 + kk*32 + (lane >> 4)*8];
    #pragma unroll
    for (int i = 0; i < 4; ++i)
      #pragma unroll
      for (int j = 0; j < 2; ++j)
        acc[i][j] = __builtin_amdgcn_mfma_f32_16x16x32_bf16(af[i], bfr[j], acc[i][j], 0, 0, 0);
  }
  // phase E: epilogue — scale, add local branch, write, track maxima
  float lm = 0.f, lmp = 0.f;
  #pragma unroll
  for (int i = 0; i < 4; ++i){
    #pragma unroll
    for (int q = 0; q < 4; ++q){
      int row = i*16 + (lane >> 4)*4 + q;
      if (row < 49){
        #pragma unroll
        for (int j = 0; j < 2; ++j){
          int col = col0 + j*16 + (lane & 15);
          float v = acc[i][j][q] * s3sv + bf2f(vlq[row*132 + col]);
          av[(size_t)(b*49 + row)*1024 + h*128 + col] = f2bf(v);
          lm = fmaxf(lm, fabsf(v));
          lmp = fmaxf(lmp, v);
        }
      }
    }
  }
  blockMaxTo(&mx[7], lm);
  blockMaxTo(&mx[8], lmp);
}

// ---------------- av -> quant(av_res) -> relu -> quant(proj_in) (IN-PLACE, x8) --------
__global__ void av2bf(const u16* av, u16* ap, const float* mx){
  const float sres = qsc(mx[7], 127.f);
  const float isres = 1.f / sres;
  const float posq = fq(mx[8], sres);
  const float spi = fmaxf(posq / 127.f, 1e-8f);
  const float ispi = 1.f / spi;
  const size_t n8 = (size_t)25088*1024/8;
  for (size_t i = (size_t)blockIdx.x*blockDim.x + threadIdx.x; i < n8; i += (size_t)gridDim.x*blockDim.x){
    bf16x8 v = *(const bf16x8*)(av + i*8);
    bf16x8 o;
    #pragma unroll
    for (int u = 0; u < 8; ++u){
      float r1 = fqi(bf2f((u16)v[u]), sres, isres);
      float r2 = fmaxf(r1, 0.f);
      o[u] = (short)f2bf(fqi(r2, spi, ispi));
    }
    *(bf16x8*)(ap + i*8) = o;
  }
}

// ---------------- y1 = x + ls1*quant(proj), absmax ----------------
__global__ __launch_bounds__(256) void res1max(
    const float* __restrict__ x, const u16* __restrict__ praw,
    const float* __restrict__ ls1, float* __restrict__ y1, float* __restrict__ mx)
{
  const int b = blockIdx.x;
  __shared__ float xs[18816];
  __shared__ float lss[384];
  const float sp = qsc(mx[9], 127.f);
  const float ip = 1.f / sp;
  const int tid = threadIdx.x;
  for (int jj = tid; jj < 4704; jj += 256)
    *(float4*)&xs[jj*4] = *(const float4*)&x[(size_t)b*18816 + jj*4];
  for (int j = tid; j < 384; j += 256) lss[j] = ls1[j];
  __syncthreads();
  float lm = 0.f;
  for (int jj = tid; jj < 4704; jj += 256){
    int j = jj*4, p = j / 384, c = j - p*384;
    s16x4 pv = *(const s16x4*)&praw[(size_t)b*18816 + j];
    float4 yv;
    #pragma unroll
    for (int u = 0; u < 4; ++u){
      float y = xs[(c+u)*49 + p] + lss[c+u] * fqi(bf2f((u16)pv[u]), sp, ip);
      ((float*)&yv)[u] = y;
      lm = fmaxf(lm, fabsf(y));
    }
    *(float4*)&y1[(size_t)b*18816 + j] = yv;
  }
  blockMaxTo(&mx[10], lm);
}

// ---------------- x1 = quant(y1): fp32 (in d_out) + bf16 copies (x4) ----------------
__global__ void qx1(const float* __restrict__ y1, float* __restrict__ x1f, u16* __restrict__ x1b,
                    const float* __restrict__ mx){
  const float s = qsc(mx[10], 127.f);
  const size_t n4 = (size_t)9633792/4;
  for (size_t i = (size_t)blockIdx.x*blockDim.x + threadIdx.x; i < n4; i += (size_t)gridDim.x*blockDim.x){
    float4 v = *(const float4*)(y1 + i*4);
    float4 o; s16x4 ob;
    #pragma unroll
    for (int u = 0; u < 4; ++u){
      float q = fq(((const float*)&v)[u], s);   // spine: exact division
      ((float*)&o)[u] = q;
      ob[u] = (short)f2bf(q);
    }
    *(float4*)(x1f + i*4) = o;
    *(s16x4*)(x1b + i*4) = ob;
  }
}

// ---------------- depthwise 3x3 (mid conv) + relu (IN-PLACE on h1) ----------------
__global__ __launch_bounds__(128) void dw_mid(
    const u16* h1, const float* wm9, const float* bmid, u16* m1, float* mx)
{
  const int cc = blockIdx.x, b = blockIdx.y;
  __shared__ float xin[49*132];
  const float sh = qsc(mx[11], 127.f);
  const float ih = 1.f / sh;
  const int tid = threadIdx.x;
  for (int j = tid; j < 784; j += 128){
    int p = j >> 4, dg = j & 15;
    const bf16x8 vv = *(const bf16x8*)&h1[(size_t)(b*49 + p)*1536 + cc*128 + dg*8];
    #pragma unroll
    for (int u = 0; u < 8; ++u)
      xin[p*132 + dg*8 + u] = fqi(bf2f((u16)vv[u]), sh, ih);
  }
  __syncthreads();
  const int c = tid;
  float w9[9];
  #pragma unroll
  for (int i = 0; i < 9; ++i) w9[i] = wm9[(cc*128 + c)*9 + i];
  const float bb = bmid[cc*128 + c];
  float col[49];
  #pragma unroll
  for (int p = 0; p < 49; ++p) col[p] = xin[p*132 + c];
  float lm = 0.f;
  #pragma unroll
  for (int p = 0; p < 49; ++p){
    const int py = p / 7, px = p % 7;
    float acc = bb;
    #pragma unroll
    for (int dy = 0; dy < 3; ++dy){
      const int yy = py + dy - 1;
      if (yy < 0 || yy > 6) continue;
      #pragma unroll
      for (int dx = 0; dx < 3; ++dx){
        const int xx = px + dx - 1;
        if (xx < 0 || xx > 6) continue;
        acc += col[yy*7 + xx] * w9[dy*3 + dx];
      }
    }
    acc = fmaxf(acc, 0.f);
    m1[(size_t)(b*49 + p)*1536 + cc*128 + c] = f2bf(acc);
    lm = fmaxf(lm, acc);
  }
  blockMaxTo(&mx[12], lm);
}

// ---------------- mid -> quant -> bf16 (IN-PLACE, x8) ----------------
__global__ void mid2bf(const u16* m1, u16* mb, const float* mx){
  const float s = qsc(mx[12], 127.f);
  const float is = 1.f / s;
  const size_t n8 = (size_t)25088*1536/8;
  for (size_t i = (size_t)blockIdx.x*blockDim.x + threadIdx.x; i < n8; i += (size_t)gridDim.x*blockDim.x){
    bf16x8 v = *(const bf16x8*)(m1 + i*8);
    bf16x8 o;
    #pragma unroll
    for (int u = 0; u < 8; ++u)
      o[u] = (short)f2bf(fqi(bf2f((u16)v[u]), s, is));
    *(bf16x8*)(mb + i*8) = o;
  }
}

// ---------------- y2 = x1 + ls2*quant(fc2), absmax (x4) ----------------
__global__ __launch_bounds__(256) void res2max(
    const float* __restrict__ x1f, const u16* __restrict__ f2,
    const float* __restrict__ ls2, float* __restrict__ y2, float* __restrict__ mx)
{
  const float s = qsc(mx[13], 127.f);
  const float is = 1.f / s;
  float lm = 0.f;
  const size_t n4 = (size_t)9633792/4;
  for (size_t i = (size_t)blockIdx.x*blockDim.x + threadIdx.x; i < n4; i += (size_t)gridDim.x*blockDim.x){
    int c0 = (int)((i*4) % 384);
    float4 xv = *(const float4*)(x1f + i*4);
    s16x4 fv = *(const s16x4*)(f2 + i*4);
    float4 yv;
    #pragma unroll
    for (int u = 0; u < 4; ++u){
      float y = ((const float*)&xv)[u] + ls2[c0+u] * fqi(bf2f((u16)fv[u]), s, is);
      ((float*)&yv)[u] = y;
      lm = fmaxf(lm, fabsf(y));
    }
    *(float4*)(y2 + i*4) = yv;
  }
  blockMaxTo(&mx[14], lm);
}

// ---------------- out2 = quant(y2), transpose to NCHW, plus out_sf ----------------
__global__ __launch_bounds__(256) void finalout(
    const float* __restrict__ y2, float* __restrict__ out, const float* __restrict__ mx)
{
  const int b = blockIdx.x;
  __shared__ float os[18816];
  const float s = qsc(mx[14], 127.f);
  const int tid = threadIdx.x;
  for (int jj = tid; jj < 4704; jj += 256){
    int j = jj*4, p = j / 384, c = j - p*384;
    float4 yv = *(const float4*)&y2[(size_t)b*18816 + j];
    #pragma unroll
    for (int u = 0; u < 4; ++u)
      os[(c+u)*49 + p] = fq(((const float*)&yv)[u], s);   // spine: exact division
  }
  __syncthreads();
  for (int jj = tid; jj < 4704; jj += 256)
    *(float4*)&out[(size_t)b*18816 + jj*4] = *(const float4*)&os[jj*4];
  if (b == 0 && tid == 0) out[9633792] = s;
}

extern "C" void kernel_launch(void* const* d_in, const int* in_sizes, int n_in,
                              void* d_out, int out_size, void* d_ws, size_t ws_size,
                              hipStream_t stream)
{
  (void)in_sizes; (void)n_in; (void)out_size; (void)ws_size;
  const float* x    = (const float*)d_in[0];
  const float* wq   = (const float*)d_in[2];
  const float* bq   = (const float*)d_in[3];
  const float* wk   = (const float*)d_in[4];
  const float* bk   = (const float*)d_in[5];
  const float* wv   = (const float*)d_in[6];
  const float* bv   = (const float*)d_in[7];
  const float* wvl  = (const float*)d_in[8];
  const float* bvl  = (const float*)d_in[9];
  const float* ab   = (const float*)d_in[10];
  const float* wth1 = (const float*)d_in[11];
  const float* bth1 = (const float*)d_in[12];
  const float* wth2 = (const float*)d_in[13];
  const float* bth2 = (const float*)d_in[14];
  const float* wproj= (const float*)d_in[15];
  const float* bproj= (const float*)d_in[16];
  const float* wfc1 = (const float*)d_in[17];
  const float* bfc1 = (const float*)d_in[18];
  const float* wmid = (const float*)d_in[19];
  const float* bmid = (const float*)d_in[20];
  const float* wfc2 = (const float*)d_in[21];
  const float* bfc2 = (const float*)d_in[22];
  const float* ls1  = (const float*)d_in[23];
  const float* ls2  = (const float*)d_in[24];
  const int*   idxs = (const int*)d_in[25];
  float* out = (float*)d_out;

  // ---- workspace layout (total 191,480,576 B ~= 183 MiB) ----
  char* w = (char*)d_ws;
  float* mx      = (float*)(w + 0);            // 256 B
  float* biasqkv = (float*)(w + 256);          // 6 KB
  u16* wqkv_b    = (u16*)(w + 6400);           // 1.18 MB
  u16* wproj_b   = (u16*)(w + 1186048);        // 786 KB
  u16* wfc1_b    = (u16*)(w + 1972480);        // 1.18 MB
  u16* wfc2_b    = (u16*)(w + 3152128);        // 1.18 MB
  float* wvl_q   = (float*)(w + 4331776);      // 36.9 KB
  float* wmid_q  = (float*)(w + 4368640);      // 55.3 KB
  float* wth1_q  = (float*)(w + 4423936);      // 256 B
  float* wth2_q  = (float*)(w + 4424192);      // 256 B
  // W1 (19.27 MB): xT -> praw -> x1b -> f2raw  (disjoint lifetimes)
  u16* xT    = (u16*)(w + 4424448);
  u16* praw  = xT;
  u16* x1b   = xT;
  u16* f2raw = xT;
  // W2 (77.07 MB): qkv -> h1 (dw_mid & mid2bf run in place)
  u16* qkv = (u16*)(w + 23692032);
  u16* h1  = qkv;
  // W4 (51.38 MB): avb (av2bf in place; then proj input)
  u16* avb = (u16*)(w + 100762368);
  // W5 (39.34 MB): S (th1k/smth2 in place) -> y1 -> y2
  float* S  = (float*)(w + 152142592);
  float* y1 = S;
  float* y2 = S;
  // x1f (38.54 MB fp32) lives in d_out; overwritten by finalout at the end
  float* x1f = out;

  zeromx<<<1, 64, 0, stream>>>(mx);
  wquant<<<6417, 128, 0, stream>>>(wq, wk, wv, wproj, wfc1, wfc2, wvl, wmid, wth1, wth2,
                                   bq, bk, bv,
                                   wqkv_b, wproj_b, wfc1_b, wfc2_b,
                                   wvl_q, wmid_q, wth1_q, wth2_q, biasqkv);
  xpose<<<512, 256, 0, stream>>>(x, xT);
  gemm_bt<<<dim3(12, 196), 256, 0, stream>>>(xT, wqkv_b, biasqkv, qkv, mx, 1536, 384, 1, 0);
  attn_qk<<<dim3(8, 512), 256, 0, stream>>>(qkv, ab, idxs, S, mx);
  vlmax<<<dim3(8, 512), 128, 0, stream>>>(qkv, wvl_q, bvl, mx);
  th1k<<<dim3(10, 512), 256, 0, stream>>>(S, wth1_q, bth1, S, mx);
  smth2<<<512, 256, 0, stream>>>(S, wth2_q, bth2, S, mx);
  attn_v<<<dim3(8, 512), 256, 0, stream>>>(qkv, S, wvl_q, bvl, avb, mx);
  av2bf<<<2048, 256, 0, stream>>>(avb, avb, mx);
  gemm_bt<<<dim3(3, 196), 256, 0, stream>>>(avb, wproj_b, bproj, praw, mx, 384, 1024, 0, 9);
  res1max<<<512, 256, 0, stream>>>(x, praw, ls1, y1, mx);
  qx1<<<2048, 256, 0, stream>>>(y1, x1f, x1b, mx);
  gemm_bt<<<dim3(12, 196), 256, 0, stream>>>(x1b, wfc1_b, bfc1, h1, mx, 1536, 384, 2, 11);
  dw_mid<<<dim3(12, 512), 128, 0, stream>>>(h1, wmid_q, bmid, h1, mx);
  mid2bf<<<2048, 256, 0, stream>>>(h1, h1, mx);
  gemm_bt<<<dim3(3, 196), 256, 0, stream>>>(h1, wfc2_b, bfc2, f2raw, mx, 384, 1536, 0, 13);
  res2max<<<2048, 256, 0, stream>>>(x1f, f2raw, ls2, y2, mx);
  finalout<<<512, 256, 0, stream>>>(y2, out, mx);
}

// Round 5
// 871.865 us; speedup vs baseline: 1.4908x; 1.0317x over previous
//
#include <hip/hip_runtime.h>

typedef unsigned short u16;
typedef unsigned int u32;
typedef float f32x4 __attribute__((ext_vector_type(4)));
typedef short bf16x8 __attribute__((ext_vector_type(8)));
typedef short s16x4 __attribute__((ext_vector_type(4)));

// ---- geometry ----
// B=512, DIM=384, RES=7, N=49, NH=8, KD=32, D=128, DH=1024, NHKD=256, HID=1536
// M = B*49 = 25088
// max-scalar table (ws offset 0):
// 0 Mq 1 Mk 2 Mv 3 Mvl 4 Mpre_th1 5 Mattn 6 Mpostsm 7 Mres_abs 8 Mres_pos
// 9 Mproj 10 Mx1 11 Mh1(relu) 12 Mmid(relu) 13 Mfc2 14 Mfinal

__device__ __forceinline__ u16 f2bf(float f){
  u32 x = __float_as_uint(f);
  x += 0x7fffu + ((x >> 16) & 1u);
  return (u16)(x >> 16);
}
__device__ __forceinline__ float bf2f(u16 u){ return __uint_as_float(((u32)u) << 16); }
__device__ __forceinline__ float qsc(float m, float qmax){ return fmaxf(m / qmax, 1e-8f); }
// exact-division fake quant (used on the residual spine)
__device__ __forceinline__ float fq(float x, float s){
  return fminf(fmaxf(rintf(x / s), -127.f), 127.f) * s;
}
// reciprocal-mul fake quant (ls1/ls2-insulated paths only)
__device__ __forceinline__ float fqi(float x, float s, float inv){
  return fminf(fmaxf(rintf(x * inv), -127.f), 127.f) * s;
}
__device__ __forceinline__ void blockMaxTo(float* target, float v){
  __shared__ float red[256];
  __syncthreads();
  red[threadIdx.x] = v;
  __syncthreads();
  for (int s = blockDim.x >> 1; s > 0; s >>= 1){
    if ((int)threadIdx.x < s) red[threadIdx.x] = fmaxf(red[threadIdx.x], red[threadIdx.x + s]);
    __syncthreads();
  }
  if (threadIdx.x == 0) atomicMax((int*)target, __float_as_int(red[0]));
}

__device__ __forceinline__ void gload16(const void* g, void* l){
  __builtin_amdgcn_global_load_lds((const __attribute__((address_space(1))) u32*)g,
                                   (__attribute__((address_space(3))) u32*)l, 16, 0, 0);
}

__global__ void zeromx(float* mx){
  if (threadIdx.x < 64) mx[threadIdx.x] = 0.f;
}

// ---------------- weight quantization (per-output-channel) ----------------
__global__ __launch_bounds__(128) void wquant(
    const float* wq, const float* wk, const float* wv, const float* wproj,
    const float* wfc1, const float* wfc2, const float* wvl, const float* wmid,
    const float* wth1, const float* wth2,
    const float* bq, const float* bk, const float* bv,
    u16* wqkv_b, u16* wproj_b, u16* wfc1_b, u16* wfc2_b,
    float* wvl_q, float* wmid_q, float* wth1_q, float* wth2_q, float* biasqkv)
{
  const int tid = threadIdx.x;
  const int bid = blockIdx.x;
  if (bid == 6416){
    for (int j = tid; j < 1536; j += 128){
      float v = (j < 256) ? bq[j] : ((j < 512) ? bk[j - 256] : bv[j - 512]);
      biasqkv[j] = v;
    }
    return;
  }
  const int rows[10] = {256,256,1024,384,1536,384,1024,1536,8,8};
  int seg = 0, r = bid;
  while (r >= rows[seg]) { r -= rows[seg]; ++seg; }
  int len = 0;
  const float* src = nullptr; u16* db = nullptr; float* df = nullptr;
  switch (seg){
    case 0: len = 384;  src = wq    + r*384;  db = wqkv_b + r*384;        break;
    case 1: len = 384;  src = wk    + r*384;  db = wqkv_b + (256+r)*384;  break;
    case 2: len = 384;  src = wv    + r*384;  db = wqkv_b + (512+r)*384;  break;
    case 3: len = 1024; src = wproj + r*1024; db = wproj_b + r*1024;      break;
    case 4: len = 384;  src = wfc1  + r*384;  db = wfc1_b + r*384;        break;
    case 5: len = 1536; src = wfc2  + r*1536; db = wfc2_b + r*1536;       break;
    case 6: len = 9;    src = wvl   + r*9;    df = wvl_q + r*9;           break;
    case 7: len = 9;    src = wmid  + r*9;    df = wmid_q + r*9;          break;
    case 8: len = 8;    src = wth1  + r*8;    df = wth1_q + r*8;          break;
    default: len = 8;   src = wth2  + r*8;    df = wth2_q + r*8;          break;
  }
  float lm = 0.f;
  for (int j = tid; j < len; j += 128) lm = fmaxf(lm, fabsf(src[j]));
  __shared__ float red[128];
  red[tid] = lm; __syncthreads();
  for (int s = 64; s > 0; s >>= 1){
    if (tid < s) red[tid] = fmaxf(red[tid], red[tid + s]);
    __syncthreads();
  }
  float s = fmaxf(red[0] / 127.f, 1e-8f);
  for (int j = tid; j < len; j += 128){
    float v = fminf(fmaxf(rintf(src[j] / s), -127.f), 127.f) * s;
    if (db) db[j] = f2bf(v); else df[j] = v;
  }
}

// ---------------- x (NCHW) -> xT [m=b*49+p][c] bf16 ----------------
__global__ __launch_bounds__(256) void xpose(const float* __restrict__ x, u16* __restrict__ xT){
  const int b = blockIdx.x;
  __shared__ u16 xb[18816];
  const int tid = threadIdx.x;
  for (int jj = tid; jj < 4704; jj += 256){
    const float4 v = *(const float4*)&x[(size_t)b*18816 + jj*4];
    xb[jj*4+0] = f2bf(v.x); xb[jj*4+1] = f2bf(v.y);
    xb[jj*4+2] = f2bf(v.z); xb[jj*4+3] = f2bf(v.w);
  }
  __syncthreads();
  for (int jj = tid; jj < 4704; jj += 256){
    int j = jj*4, p = j / 384, c = j - p*384;
    s16x4 o;
    #pragma unroll
    for (int u = 0; u < 4; ++u) o[u] = (short)xb[(c+u)*49 + p];
    *(s16x4*)&xT[(size_t)b*18816 + j] = o;
  }
}

// ---------------- bf16 MFMA GEMM: C[M][N] = A[M][K] * Bt[N][K]^T + bias ----------------
// Staging via global_load_lds width-16 (direct HBM->LDS, no VGPR round-trip).
// epi: 0 = absmax, 1 = qkv (3 regions by n0), 2 = relu then posmax. C written as bf16.
__global__ __launch_bounds__(256) void gemm_bt(
    const u16* __restrict__ A, const u16* __restrict__ Bt,
    const float* __restrict__ bias, u16* __restrict__ C,
    float* __restrict__ mx, int N, int K, int epi, int region)
{
  __shared__ __align__(16) u16 As[128*64];
  __shared__ __align__(16) u16 Bs[128*64];
  const int tid = threadIdx.x;
  const int lane = tid & 63, wid = tid >> 6;
  const int n0 = blockIdx.x * 128;
  const int m0 = blockIdx.y * 128;
  const int wr = wid >> 1, wc = wid & 1;
  f32x4 acc[4][4] = {};
  const int nsteps = K >> 6;
  for (int s = 0; s < nsteps; ++s){
    const int k0 = s << 6;
    #pragma unroll
    for (int j = 0; j < 4; ++j){
      int boff = j*4096 + tid*16;      // byte offset into As/Bs (wave-linear)
      int row = boff >> 7;
      int ce  = (boff & 127) >> 1;
      gload16(A  + (size_t)(m0 + row)*K + k0 + ce, (char*)As + boff);
      gload16(Bt + (size_t)(n0 + row)*K + k0 + ce, (char*)Bs + boff);
    }
    __syncthreads();
    #pragma unroll
    for (int kk = 0; kk < 2; ++kk){
      bf16x8 af[4], bfr[4];
      #pragma unroll
      for (int i = 0; i < 4; ++i){
        int ar = wr*64 + i*16 + (lane & 15);
        af[i]  = *(const bf16x8*)&As[ar*64 + kk*32 + (lane >> 4)*8];
        int br = wc*64 + i*16 + (lane & 15);
        bfr[i] = *(const bf16x8*)&Bs[br*64 + kk*32 + (lane >> 4)*8];
      }
      #pragma unroll
      for (int i = 0; i < 4; ++i){
        #pragma unroll
        for (int j = 0; j < 4; ++j){
          acc[i][j] = __builtin_amdgcn_mfma_f32_16x16x32_bf16(af[i], bfr[j], acc[i][j], 0, 0, 0);
        }
      }
    }
    __syncthreads();
  }
  float lm = 0.f;
  #pragma unroll
  for (int i = 0; i < 4; ++i){
    int rbase = m0 + wr*64 + i*16 + ((lane >> 4) << 2);
    #pragma unroll
    for (int j = 0; j < 4; ++j){
      int col = n0 + wc*64 + j*16 + (lane & 15);
      float bv = bias[col];
      #pragma unroll
      for (int q = 0; q < 4; ++q){
        float v = acc[i][j][q] + bv;
        if (epi == 2) v = fmaxf(v, 0.f);
        C[(size_t)(rbase + q)*N + col] = f2bf(v);
        lm = fmaxf(lm, (epi == 2) ? v : fabsf(v));
      }
    }
  }
  int reg = region;
  if (epi == 1) reg = (n0 < 256) ? 0 : ((n0 < 512) ? 1 : 2);
  blockMaxTo(&mx[reg], lm);
}

// ---------------- depthwise 3x3 local-V absmax only (no output) ----------------
__global__ __launch_bounds__(128) void vlmax(
    const u16* __restrict__ qkv, const float* __restrict__ wv9,
    const float* __restrict__ bvl, float* __restrict__ mx)
{
  const int cc = blockIdx.x, b = blockIdx.y;   // cc = head (128-ch group)
  __shared__ float xin[49*132];
  const float sv = qsc(mx[2], 127.f);
  const float iv = 1.f / sv;
  const int tid = threadIdx.x;
  for (int j = tid; j < 784; j += 128){
    int p = j >> 4, dg = j & 15;
    const bf16x8 vv = *(const bf16x8*)&qkv[(size_t)(b*49 + p)*1536 + 512 + cc*128 + dg*8];
    #pragma unroll
    for (int u = 0; u < 8; ++u)
      xin[p*132 + dg*8 + u] = fqi(bf2f((u16)vv[u]), sv, iv);
  }
  __syncthreads();
  const int c = tid;
  float w9[9];
  #pragma unroll
  for (int i = 0; i < 9; ++i) w9[i] = wv9[(cc*128 + c)*9 + i];
  const float bb = bvl[cc*128 + c];
  float col[49];
  #pragma unroll
  for (int p = 0; p < 49; ++p) col[p] = xin[p*132 + c];
  float lm = 0.f;
  #pragma unroll
  for (int p = 0; p < 49; ++p){
    const int py = p / 7, px = p % 7;
    float acc = bb;
    #pragma unroll
    for (int dy = 0; dy < 3; ++dy){
      const int yy = py + dy - 1;
      if (yy < 0 || yy > 6) continue;
      #pragma unroll
      for (int dx = 0; dx < 3; ++dx){
        const int xx = px + dx - 1;
        if (xx < 0 || xx > 6) continue;
        acc += col[yy*7 + xx] * w9[dy*3 + dx];
      }
    }
    lm = fmaxf(lm, fabsf(acc));
  }
  blockMaxTo(&mx[3], lm);
}

// ---------------- S = q*k^T*scale + bias ----------------
__global__ __launch_bounds__(256) void attn_qk(
    const u16* __restrict__ qkv, const float* __restrict__ biases,
    const int* __restrict__ idxs, float* __restrict__ S, float* __restrict__ mx)
{
  const int h = blockIdx.x, b = blockIdx.y;
  __shared__ float qs[49*32];
  __shared__ float ks[49*33];
  __shared__ float brow[49];
  const float sq = qsc(mx[0], 127.f), sk = qsc(mx[1], 127.f);
  const float iq = 1.f/sq, ik = 1.f/sk;
  const int tid = threadIdx.x;
  for (int j = tid; j < 196; j += 256){
    int n = j >> 2, d0 = (j & 3)*8;
    size_t base = (size_t)(b*49 + n)*1536;
    const bf16x8 qv = *(const bf16x8*)&qkv[base + h*32 + d0];
    const bf16x8 kv = *(const bf16x8*)&qkv[base + 256 + h*32 + d0];
    #pragma unroll
    for (int u = 0; u < 8; ++u){
      qs[n*32 + d0 + u] = fqi(bf2f((u16)qv[u]), sq, iq);
      ks[n*33 + d0 + u] = fqi(bf2f((u16)kv[u]), sk, ik);
    }
  }
  if (tid < 49) brow[tid] = biases[h*49 + tid];
  __syncthreads();
  float lm = 0.f;
  const float scale = 0.17677669529663687f;
  for (int t = tid; t < 2401; t += 256){
    int n = t / 49, m = t - n*49;
    float acc = 0.f;
    #pragma unroll
    for (int kd = 0; kd < 32; ++kd) acc += qs[n*32 + kd] * ks[m*33 + kd];
    float v = acc * scale + brow[idxs[t]];
    S[((size_t)b*8 + h)*2401 + t] = v;
    lm = fmaxf(lm, fabsf(v));
  }
  blockMaxTo(&mx[4], lm);
}

// ---------------- talking head 1 (IN-PLACE on S; no restrict!) ----------------
__global__ __launch_bounds__(256) void th1k(
    const float* S, const float* w1, const float* b1, float* T, float* mx)
{
  const int b = blockIdx.y;
  const int j = blockIdx.x*256 + threadIdx.x;
  __shared__ float wsh[64];
  __shared__ float bsh[8];
  if (threadIdx.x < 64) wsh[threadIdx.x] = w1[threadIdx.x];
  if (threadIdx.x < 8)  bsh[threadIdx.x] = b1[threadIdx.x];
  __syncthreads();
  float lm = 0.f;
  if (j < 2401){
    const float s1 = qsc(mx[4], 127.f);
    const float i1 = 1.f/s1;
    float a[8];
    #pragma unroll
    for (int h = 0; h < 8; ++h) a[h] = fqi(S[((size_t)b*8 + h)*2401 + j], s1, i1);
    float o8[8];
    #pragma unroll
    for (int o = 0; o < 8; ++o){
      float t = bsh[o];
      #pragma unroll
      for (int h = 0; h < 8; ++h) t += wsh[o*8 + h] * a[h];
      o8[o] = t;
      lm = fmaxf(lm, fabsf(t));
    }
    #pragma unroll
    for (int o = 0; o < 8; ++o) T[((size_t)b*8 + o)*2401 + j] = o8[o];
  }
  blockMaxTo(&mx[5], lm);
}

// ---------------- int softmax (I-BERT) + talking head 2 (IN-PLACE) ----------------
__global__ __launch_bounds__(256) void smth2(
    const float* T, const float* w2, const float* b2, float* U, float* mx)
{
  const int b = blockIdx.x;
  __shared__ float P[19208];
  __shared__ float wsh[64];
  __shared__ float bsh[8];
  const float sa = qsc(mx[5], 127.f);
  const int tid = threadIdx.x;
  if (tid < 64) wsh[tid] = w2[tid];
  if (tid < 8)  bsh[tid] = b2[tid];
  for (int j = tid; j < 19208; j += 256){
    float v = T[(size_t)b*19208 + j];
    P[j] = fminf(fmaxf(rintf(v / sa), -127.f), 127.f);   // integer-valued
  }
  __syncthreads();
  const float x0 = floorf(-0.6931f / sa);
  const float bi = floorf((0.96963238f / 0.35815147f) / sa);
  const float ci = floorf((1.0f / 0.35815147f) / (sa * sa));
  const float Kc = ((0.35815147f * sa) * sa) * (1.f/1073741824.f);
  const float maxv = (ci * 1073741824.f) * Kc;     // analytic global max of exp tensor
  const float se = fmaxf(maxv / 32767.f, 1e-8f);
  const float clampLo = 30.f * x0;
  for (int row = tid; row < 392; row += 256){
    float* pr = &P[row*49];
    float rmax = pr[0];
    for (int m = 1; m < 49; ++m) rmax = fmaxf(rmax, pr[m]);
    float rsum = 0.f;
    for (int m = 0; m < 49; ++m){
      float xi = pr[m] - rmax;
      xi = fmaxf(xi, clampLo);
      float qd = floorf(xi / x0);
      float r = xi - x0*qd;
      float z = (r + bi)*r + ci;
      float ei = floorf(z * exp2f(30.f - qd));
      ei = fmaxf(ei, 0.f);
      float t = ei * Kc;
      float e2 = fminf(fmaxf(rintf(t / se), -32767.f), 32767.f);
      float eint = (e2 * se) / se;
      pr[m] = eint;
      rsum += eint;
    }
    const float factor = floorf(4294967296.f / rsum);
    for (int m = 0; m < 49; ++m){
      pr[m] = floorf((pr[m] * factor) * (1.f/65536.f)) * (1.f/65536.f);
    }
  }
  __syncthreads();
  float lm = 0.f;
  for (int j = tid; j < 19208; j += 256){
    int o = j / 2401, rem = j - o*2401;
    float t = bsh[o];
    #pragma unroll
    for (int h = 0; h < 8; ++h) t += wsh[o*8 + h] * P[h*2401 + rem];
    U[(size_t)b*19208 + j] = t;
    lm = fmaxf(lm, fabsf(t));
  }
  blockMaxTo(&mx[6], lm);
}

// ---------------- out = attn_q @ v_q + fq(dwconv(v_q)) — MFMA, lean-LDS version ----
// P and V quantized to INTEGER-valued bf16 (|k|<=127 exact); MFMA accumulates the exact
// integer product; epilogue applies s3*sv once and computes the depthwise-3x3 local
// branch inline from Vt (weights in registers). One __syncthreads on the main path.
__global__ __launch_bounds__(256) void attn_v(
    const u16* __restrict__ qkv, const float* __restrict__ U,
    const float* __restrict__ wv9, const float* __restrict__ bvl,
    u16* __restrict__ av, float* __restrict__ mx)
{
  const int h = blockIdx.x, b = blockIdx.y;
  __shared__ __align__(16) u16 Pb[64*68];     // [n][k=m] int-valued bf16, stride 68
  __shared__ __align__(16) u16 Vt[128*66];    // [d][k=m] int-valued bf16, stride 66
  const float s3 = qsc(mx[6], 127.f), sv = qsc(mx[2], 127.f), svl = qsc(mx[3], 127.f);
  const float i3 = 1.f/s3, iv = 1.f/sv, il = 1.f/svl;
  const float s3sv = s3 * sv;
  const int tid = threadIdx.x;
  const int lane = tid & 63, wid = tid >> 6;
  const int col0 = wid * 32;
  const int ca = col0 + (lane & 15), cb = ca + 16;   // the two columns this thread owns
  // conv weights + bias for owned columns -> registers (wv9/bvl are L2-resident)
  float wA[9], wB[9];
  #pragma unroll
  for (int t = 0; t < 9; ++t){
    wA[t] = wv9[h*1152 + ca*9 + t];
    wB[t] = wv9[h*1152 + cb*9 + t];
  }
  const float bvA = bvl[h*128 + ca], bvB = bvl[h*128 + cb];
  // zero k-pad columns only (k in [49,68)/[49,66)); rows >=49 of output are discarded
  for (int j = tid; j < 64*19; j += 256){ int n = j/19, m = 49 + (j - n*19); Pb[n*68 + m] = 0; }
  for (int j = tid; j < 128*17; j += 256){ int d = j/17, m = 49 + (j - d*17); Vt[d*66 + m] = 0; }
  // P-quant: integer-valued bf16
  for (int j = tid; j < 2401; j += 256){
    int n = j / 49, m = j - n*49;
    float k = fminf(fmaxf(rintf(U[((size_t)b*8 + h)*2401 + j] * i3), -127.f), 127.f);
    Pb[n*68 + m] = f2bf(k);
  }
  // V-quant, d-major (coalesced u32 loads; low-conflict stride-66 scatter writes)
  {
    const int dp = (lane) * 2, mc = wid;     // 64 d-pairs x 4 m-chunks
    const int mend = (mc == 3) ? 49 : (mc*13 + 13);
    const size_t base = (size_t)(b*49)*1536 + 512 + h*128 + dp;
    for (int m = mc*13; m < mend; ++m){
      u32 two = *(const u32*)&qkv[base + (size_t)m*1536];
      float k0 = fminf(fmaxf(rintf(bf2f((u16)(two & 0xffffu)) * iv), -127.f), 127.f);
      float k1 = fminf(fmaxf(rintf(bf2f((u16)(two >> 16)) * iv), -127.f), 127.f);
      Vt[dp*66 + m]       = f2bf(k0);
      Vt[(dp + 1)*66 + m] = f2bf(k1);
    }
  }
  __syncthreads();
  // MFMA: P(64x64) x V^T(64x128) — per wave 64 rows x 32 cols
  f32x4 acc[4][2] = {};
  #pragma unroll
  for (int kk = 0; kk < 2; ++kk){
    bf16x8 af[4], bfr[2];
    #pragma unroll
    for (int i = 0; i < 4; ++i)
      af[i] = *(const bf16x8*)&Pb[(i*16 + (lane & 15))*68 + kk*32 + (lane >> 4)*8];
    #pragma unroll
    for (int j = 0; j < 2; ++j)
      bfr[j] = *(const bf16x8*)&Vt[(col0 + j*16 + (lane & 15))*66 + kk*32 + (lane >> 4)*8];
    #pragma unroll
    for (int i = 0; i < 4; ++i)
      #pragma unroll
      for (int j = 0; j < 2; ++j)
        acc[i][j] = __builtin_amdgcn_mfma_f32_16x16x32_bf16(af[i], bfr[j], acc[i][j], 0, 0, 0);
  }
  // epilogue: inline depthwise-3x3 local branch + scale + write + maxima
  float lm = 0.f, lmp = 0.f;
  #pragma unroll
  for (int i = 0; i < 4; ++i){
    #pragma unroll
    for (int q = 0; q < 4; ++q){
      const int row = i*16 + ((lane >> 4) << 2) + q;
      if (row < 49){
        const int py = row / 7, px = row - py*7;
        float cA = 0.f, cB = 0.f;
        #pragma unroll
        for (int dy = 0; dy < 3; ++dy){
          const int yy = py + dy - 1;
          if (yy < 0 || yy > 6) continue;
          #pragma unroll
          for (int dx = 0; dx < 3; ++dx){
            const int xx = px + dx - 1;
            if (xx < 0 || xx > 6) continue;
            const int t = dy*3 + dx, p9 = yy*7 + xx;
            cA += bf2f(Vt[ca*66 + p9]) * wA[t];
            cB += bf2f(Vt[cb*66 + p9]) * wB[t];
          }
        }
        const float vA = acc[i][0][q] * s3sv + fqi(sv*cA + bvA, svl, il);
        const float vB = acc[i][1][q] * s3sv + fqi(sv*cB + bvB, svl, il);
        av[(size_t)(b*49 + row)*1024 + h*128 + ca] = f2bf(vA);
        av[(size_t)(b*49 + row)*1024 + h*128 + cb] = f2bf(vB);
        lm = fmaxf(lm, fmaxf(fabsf(vA), fabsf(vB)));
        lmp = fmaxf(lmp, fmaxf(vA, vB));
      }
    }
  }
  blockMaxTo(&mx[7], lm);
  blockMaxTo(&mx[8], lmp);
}

// ---------------- av -> quant(av_res) -> relu -> quant(proj_in) (IN-PLACE, x8) --------
__global__ void av2bf(const u16* av, u16* ap, const float* mx){
  const float sres = qsc(mx[7], 127.f);
  const float isres = 1.f / sres;
  const float posq = fq(mx[8], sres);
  const float spi = fmaxf(posq / 127.f, 1e-8f);
  const float ispi = 1.f / spi;
  const size_t n8 = (size_t)25088*1024/8;
  for (size_t i = (size_t)blockIdx.x*blockDim.x + threadIdx.x; i < n8; i += (size_t)gridDim.x*blockDim.x){
    bf16x8 v = *(const bf16x8*)(av + i*8);
    bf16x8 o;
    #pragma unroll
    for (int u = 0; u < 8; ++u){
      float r1 = fqi(bf2f((u16)v[u]), sres, isres);
      float r2 = fmaxf(r1, 0.f);
      o[u] = (short)f2bf(fqi(r2, spi, ispi));
    }
    *(bf16x8*)(ap + i*8) = o;
  }
}

// ---------------- y1 = x + ls1*quant(proj), absmax ----------------
__global__ __launch_bounds__(256) void res1max(
    const float* __restrict__ x, const u16* __restrict__ praw,
    const float* __restrict__ ls1, float* __restrict__ y1, float* __restrict__ mx)
{
  const int b = blockIdx.x;
  __shared__ float xs[18816];
  __shared__ float lss[384];
  const float sp = qsc(mx[9], 127.f);
  const float ip = 1.f / sp;
  const int tid = threadIdx.x;
  for (int jj = tid; jj < 4704; jj += 256)
    *(float4*)&xs[jj*4] = *(const float4*)&x[(size_t)b*18816 + jj*4];
  for (int j = tid; j < 384; j += 256) lss[j] = ls1[j];
  __syncthreads();
  float lm = 0.f;
  for (int jj = tid; jj < 4704; jj += 256){
    int j = jj*4, p = j / 384, c = j - p*384;
    s16x4 pv = *(const s16x4*)&praw[(size_t)b*18816 + j];
    float4 yv;
    #pragma unroll
    for (int u = 0; u < 4; ++u){
      float y = xs[(c+u)*49 + p] + lss[c+u] * fqi(bf2f((u16)pv[u]), sp, ip);
      ((float*)&yv)[u] = y;
      lm = fmaxf(lm, fabsf(y));
    }
    *(float4*)&y1[(size_t)b*18816 + j] = yv;
  }
  blockMaxTo(&mx[10], lm);
}

// ---------------- x1 = quant(y1): fp32 (in d_out) + bf16 copies (x4) ----------------
__global__ void qx1(const float* __restrict__ y1, float* __restrict__ x1f, u16* __restrict__ x1b,
                    const float* __restrict__ mx){
  const float s = qsc(mx[10], 127.f);
  const size_t n4 = (size_t)9633792/4;
  for (size_t i = (size_t)blockIdx.x*blockDim.x + threadIdx.x; i < n4; i += (size_t)gridDim.x*blockDim.x){
    float4 v = *(const float4*)(y1 + i*4);
    float4 o; s16x4 ob;
    #pragma unroll
    for (int u = 0; u < 4; ++u){
      float q = fq(((const float*)&v)[u], s);   // spine: exact division
      ((float*)&o)[u] = q;
      ob[u] = (short)f2bf(q);
    }
    *(float4*)(x1f + i*4) = o;
    *(s16x4*)(x1b + i*4) = ob;
  }
}

// ---------------- depthwise 3x3 (mid conv) + relu (IN-PLACE on h1) ----------------
__global__ __launch_bounds__(128) void dw_mid(
    const u16* h1, const float* wm9, const float* bmid, u16* m1, float* mx)
{
  const int cc = blockIdx.x, b = blockIdx.y;
  __shared__ float xin[49*132];
  const float sh = qsc(mx[11], 127.f);
  const float ih = 1.f / sh;
  const int tid = threadIdx.x;
  for (int j = tid; j < 784; j += 128){
    int p = j >> 4, dg = j & 15;
    const bf16x8 vv = *(const bf16x8*)&h1[(size_t)(b*49 + p)*1536 + cc*128 + dg*8];
    #pragma unroll
    for (int u = 0; u < 8; ++u)
      xin[p*132 + dg*8 + u] = fqi(bf2f((u16)vv[u]), sh, ih);
  }
  __syncthreads();
  const int c = tid;
  float w9[9];
  #pragma unroll
  for (int i = 0; i < 9; ++i) w9[i] = wm9[(cc*128 + c)*9 + i];
  const float bb = bmid[cc*128 + c];
  float col[49];
  #pragma unroll
  for (int p = 0; p < 49; ++p) col[p] = xin[p*132 + c];
  float lm = 0.f;
  #pragma unroll
  for (int p = 0; p < 49; ++p){
    const int py = p / 7, px = p % 7;
    float acc = bb;
    #pragma unroll
    for (int dy = 0; dy < 3; ++dy){
      const int yy = py + dy - 1;
      if (yy < 0 || yy > 6) continue;
      #pragma unroll
      for (int dx = 0; dx < 3; ++dx){
        const int xx = px + dx - 1;
        if (xx < 0 || xx > 6) continue;
        acc += col[yy*7 + xx] * w9[dy*3 + dx];
      }
    }
    acc = fmaxf(acc, 0.f);
    m1[(size_t)(b*49 + p)*1536 + cc*128 + c] = f2bf(acc);
    lm = fmaxf(lm, acc);
  }
  blockMaxTo(&mx[12], lm);
}

// ---------------- mid -> quant -> bf16 (IN-PLACE, x8) ----------------
__global__ void mid2bf(const u16* m1, u16* mb, const float* mx){
  const float s = qsc(mx[12], 127.f);
  const float is = 1.f / s;
  const size_t n8 = (size_t)25088*1536/8;
  for (size_t i = (size_t)blockIdx.x*blockDim.x + threadIdx.x; i < n8; i += (size_t)gridDim.x*blockDim.x){
    bf16x8 v = *(const bf16x8*)(m1 + i*8);
    bf16x8 o;
    #pragma unroll
    for (int u = 0; u < 8; ++u)
      o[u] = (short)f2bf(fqi(bf2f((u16)v[u]), s, is));
    *(bf16x8*)(mb + i*8) = o;
  }
}

// ---------------- y2 = x1 + ls2*quant(fc2), absmax (x4) ----------------
__global__ __launch_bounds__(256) void res2max(
    const float* __restrict__ x1f, const u16* __restrict__ f2,
    const float* __restrict__ ls2, float* __restrict__ y2, float* __restrict__ mx)
{
  const float s = qsc(mx[13], 127.f);
  const float is = 1.f / s;
  float lm = 0.f;
  const size_t n4 = (size_t)9633792/4;
  for (size_t i = (size_t)blockIdx.x*blockDim.x + threadIdx.x; i < n4; i += (size_t)gridDim.x*blockDim.x){
    int c0 = (int)((i*4) % 384);
    float4 xv = *(const float4*)(x1f + i*4);
    s16x4 fv = *(const s16x4*)(f2 + i*4);
    float4 yv;
    #pragma unroll
    for (int u = 0; u < 4; ++u){
      float y = ((const float*)&xv)[u] + ls2[c0+u] * fqi(bf2f((u16)fv[u]), s, is);
      ((float*)&yv)[u] = y;
      lm = fmaxf(lm, fabsf(y));
    }
    *(float4*)(y2 + i*4) = yv;
  }
  blockMaxTo(&mx[14], lm);
}

// ---------------- out2 = quant(y2), transpose to NCHW, plus out_sf ----------------
__global__ __launch_bounds__(256) void finalout(
    const float* __restrict__ y2, float* __restrict__ out, const float* __restrict__ mx)
{
  const int b = blockIdx.x;
  __shared__ float os[18816];
  const float s = qsc(mx[14], 127.f);
  const int tid = threadIdx.x;
  for (int jj = tid; jj < 4704; jj += 256){
    int j = jj*4, p = j / 384, c = j - p*384;
    float4 yv = *(const float4*)&y2[(size_t)b*18816 + j];
    #pragma unroll
    for (int u = 0; u < 4; ++u)
      os[(c+u)*49 + p] = fq(((const float*)&yv)[u], s);   // spine: exact division
  }
  __syncthreads();
  for (int jj = tid; jj < 4704; jj += 256)
    *(float4*)&out[(size_t)b*18816 + jj*4] = *(const float4*)&os[jj*4];
  if (b == 0 && tid == 0) out[9633792] = s;
}

extern "C" void kernel_launch(void* const* d_in, const int* in_sizes, int n_in,
                              void* d_out, int out_size, void* d_ws, size_t ws_size,
                              hipStream_t stream)
{
  (void)in_sizes; (void)n_in; (void)out_size; (void)ws_size;
  const float* x    = (const float*)d_in[0];
  const float* wq   = (const float*)d_in[2];
  const float* bq   = (const float*)d_in[3];
  const float* wk   = (const float*)d_in[4];
  const float* bk   = (const float*)d_in[5];
  const float* wv   = (const float*)d_in[6];
  const float* bv   = (const float*)d_in[7];
  const float* wvl  = (const float*)d_in[8];
  const float* bvl  = (const float*)d_in[9];
  const float* ab   = (const float*)d_in[10];
  const float* wth1 = (const float*)d_in[11];
  const float* bth1 = (const float*)d_in[12];
  const float* wth2 = (const float*)d_in[13];
  const float* bth2 = (const float*)d_in[14];
  const float* wproj= (const float*)d_in[15];
  const float* bproj= (const float*)d_in[16];
  const float* wfc1 = (const float*)d_in[17];
  const float* bfc1 = (const float*)d_in[18];
  const float* wmid = (const float*)d_in[19];
  const float* bmid = (const float*)d_in[20];
  const float* wfc2 = (const float*)d_in[21];
  const float* bfc2 = (const float*)d_in[22];
  const float* ls1  = (const float*)d_in[23];
  const float* ls2  = (const float*)d_in[24];
  const int*   idxs = (const int*)d_in[25];
  float* out = (float*)d_out;

  // ---- workspace layout (total 191,480,576 B ~= 183 MiB) ----
  char* w = (char*)d_ws;
  float* mx      = (float*)(w + 0);            // 256 B
  float* biasqkv = (float*)(w + 256);          // 6 KB
  u16* wqkv_b    = (u16*)(w + 6400);           // 1.18 MB
  u16* wproj_b   = (u16*)(w + 1186048);        // 786 KB
  u16* wfc1_b    = (u16*)(w + 1972480);        // 1.18 MB
  u16* wfc2_b    = (u16*)(w + 3152128);        // 1.18 MB
  float* wvl_q   = (float*)(w + 4331776);      // 36.9 KB
  float* wmid_q  = (float*)(w + 4368640);      // 55.3 KB
  float* wth1_q  = (float*)(w + 4423936);      // 256 B
  float* wth2_q  = (float*)(w + 4424192);      // 256 B
  // W1 (19.27 MB): xT -> praw -> x1b -> f2raw  (disjoint lifetimes)
  u16* xT    = (u16*)(w + 4424448);
  u16* praw  = xT;
  u16* x1b   = xT;
  u16* f2raw = xT;
  // W2 (77.07 MB): qkv -> h1 (dw_mid & mid2bf run in place)
  u16* qkv = (u16*)(w + 23692032);
  u16* h1  = qkv;
  // W4 (51.38 MB): avb (av2bf in place; then proj input)
  u16* avb = (u16*)(w + 100762368);
  // W5 (39.34 MB): S (th1k/smth2 in place) -> y1 -> y2
  float* S  = (float*)(w + 152142592);
  float* y1 = S;
  float* y2 = S;
  // x1f (38.54 MB fp32) lives in d_out; overwritten by finalout at the end
  float* x1f = out;

  zeromx<<<1, 64, 0, stream>>>(mx);
  wquant<<<6417, 128, 0, stream>>>(wq, wk, wv, wproj, wfc1, wfc2, wvl, wmid, wth1, wth2,
                                   bq, bk, bv,
                                   wqkv_b, wproj_b, wfc1_b, wfc2_b,
                                   wvl_q, wmid_q, wth1_q, wth2_q, biasqkv);
  xpose<<<512, 256, 0, stream>>>(x, xT);
  gemm_bt<<<dim3(12, 196), 256, 0, stream>>>(xT, wqkv_b, biasqkv, qkv, mx, 1536, 384, 1, 0);
  attn_qk<<<dim3(8, 512), 256, 0, stream>>>(qkv, ab, idxs, S, mx);
  vlmax<<<dim3(8, 512), 128, 0, stream>>>(qkv, wvl_q, bvl, mx);
  th1k<<<dim3(10, 512), 256, 0, stream>>>(S, wth1_q, bth1, S, mx);
  smth2<<<512, 256, 0, stream>>>(S, wth2_q, bth2, S, mx);
  attn_v<<<dim3(8, 512), 256, 0, stream>>>(qkv, S, wvl_q, bvl, avb, mx);
  av2bf<<<2048, 256, 0, stream>>>(avb, avb, mx);
  gemm_bt<<<dim3(3, 196), 256, 0, stream>>>(avb, wproj_b, bproj, praw, mx, 384, 1024, 0, 9);
  res1max<<<512, 256, 0, stream>>>(x, praw, ls1, y1, mx);
  qx1<<<2048, 256, 0, stream>>>(y1, x1f, x1b, mx);
  gemm_bt<<<dim3(12, 196), 256, 0, stream>>>(x1b, wfc1_b, bfc1, h1, mx, 1536, 384, 2, 11);
  dw_mid<<<dim3(12, 512), 128, 0, stream>>>(h1, wmid_q, bmid, h1, mx);
  mid2bf<<<2048, 256, 0, stream>>>(h1, h1, mx);
  gemm_bt<<<dim3(3, 196), 256, 0, stream>>>(h1, wfc2_b, bfc2, f2raw, mx, 384, 1536, 0, 13);
  res2max<<<2048, 256, 0, stream>>>(x1f, f2raw, ls2, y2, mx);
  finalout<<<512, 256, 0, stream>>>(y2, out, mx);
}